// Round 9
// baseline (2971.373 us; speedup 1.0000x reference)
//
#include <hip/hip_runtime.h>
#include <math.h>

#define LRELU(v) ((v) >= 0.f ? (v) : 0.2f*(v))

__device__ __forceinline__ float sigmoidf_(float x){ return 1.f/(1.f + expf(-x)); }

typedef __attribute__((ext_vector_type(8))) short bf16x8;
typedef __attribute__((ext_vector_type(4))) float f32x4;
typedef __attribute__((ext_vector_type(8))) unsigned short u16x8;
typedef __attribute__((ext_vector_type(4))) unsigned short u16x4;

__device__ __forceinline__ unsigned short bf16_rne(float x){
    union { float f; unsigned u; } v; v.f = x;
    unsigned r = v.u + 0x7fffu + ((v.u >> 16) & 1u);
    return (unsigned short)(r >> 16);
}
__device__ __forceinline__ float bf16_tof(unsigned short h){
    union { float f; unsigned u; } v; v.u = ((unsigned)h) << 16; return v.f;
}
__device__ __forceinline__ void bsplit(float x, unsigned short& hi, unsigned short& lo){
    hi = bf16_rne(x);
    lo = bf16_rne(x - bf16_tof(hi));
}

// ---------------------------------------------------------------------------
// conv1: x (Nimg,1,128,128) -> e1 (Nimg,16,64,64) fp32 ch-first, k3 s2 p1.
// ---------------------------------------------------------------------------
__global__ __launch_bounds__(256) void k_conv1(const float* __restrict__ x,
    const float* __restrict__ W, const float* __restrict__ Bb, float* __restrict__ out)
{
    __shared__ float wl[144];
    __shared__ float bl[16];
    int tid = threadIdx.x;
    if (tid < 144) { int oc = tid/9, tap = tid%9; wl[tap*16+oc] = W[oc*9+tap]; }
    if (tid < 16) bl[tid] = Bb[tid];
    __syncthreads();
    int img = blockIdx.y;
    int px = blockIdx.x*256 + tid;
    int oy = px >> 6, ox = px & 63;
    const float* xin = x + (size_t)img*16384;
    float acc[16];
    #pragma unroll
    for (int o=0;o<16;++o) acc[o]=bl[o];
    #pragma unroll
    for (int kh=0; kh<3; ++kh){
        int iy = 2*oy + kh - 1;
        bool vy = (iy>=0 && iy<128);
        #pragma unroll
        for (int kw=0; kw<3; ++kw){
            int ix = 2*ox + kw - 1;
            float v = (vy && ix>=0 && ix<128) ? xin[iy*128+ix] : 0.f;
            int tap = kh*3+kw;
            #pragma unroll
            for (int o=0;o<16;++o) acc[o] += wl[tap*16+o]*v;
        }
    }
    float* op = out + (size_t)img*65536 + px;
    #pragma unroll
    for (int o=0;o<16;++o){ float v = acc[o]; op[o*4096] = LRELU(v); }
}

// ---------------------------------------------------------------------------
// conv2: e1 (Nimg,16,64,64) -> e2 split bf16 hi/lo CHANNEL-LAST [img][1024][64]
// ---------------------------------------------------------------------------
__global__ __launch_bounds__(256) void k_conv2(const float* __restrict__ in,
    const float* __restrict__ W, const float* __restrict__ Bb,
    unsigned short* __restrict__ e2hi, unsigned short* __restrict__ e2lo)
{
    __shared__ float tile[2*65*68];
    __shared__ float wl[2*9*16];
    int tid = threadIdx.x;
    int img = blockIdx.y;
    int ocBase = blockIdx.x*16;
    int y = tid >> 3, xg = tid & 7, x0 = xg*4;
    float acc[16][4];
    #pragma unroll
    for (int o=0;o<16;++o){ float b = Bb[ocBase+o];
        #pragma unroll
        for (int p=0;p<4;++p) acc[o][p] = b; }
    const float* base = in + (size_t)img*65536;
    for (int icB=0; icB<16; icB+=2){
        for (int e=tid; e<2210; e+=256){            // 2*65*17 float4
            int c4 = e % 17; int rr = (e/17)%65; int ch = e/(17*65);
            int iy = rr - 1; int ixb = c4*4 - 4;
            float4 v = make_float4(0.f,0.f,0.f,0.f);
            if (iy>=0 && iy<64 && c4>=1)
                v = *(const float4*)(base + (icB+ch)*4096 + iy*64 + ixb);
            *(float4*)(&tile[ch*4420 + rr*68 + c4*4]) = v;
        }
        for (int e=tid; e<288; e+=256){
            int oc = e & 15; int rest = e >> 4; int tap = rest % 9; int ch = rest/9;
            wl[(ch*9+tap)*16 + oc] = W[((ocBase+oc)*16 + icB+ch)*9 + tap];
        }
        __syncthreads();
        #pragma unroll
        for (int ch=0; ch<2; ++ch){
            #pragma unroll
            for (int kh=0; kh<3; ++kh){
                int r = 2*y + kh;
                const float4* row = (const float4*)(&tile[ch*4420 + r*68 + 2*x0]);
                float4 a0=row[0], a1=row[1], a2=row[2];
                float win[12] = {a0.x,a0.y,a0.z,a0.w,a1.x,a1.y,a1.z,a1.w,a2.x,a2.y,a2.z,a2.w};
                #pragma unroll
                for (int kw=0; kw<3; ++kw){
                    const float4* wp = (const float4*)(&wl[(ch*9+kh*3+kw)*16]);
                    float4 w0=wp[0], w1=wp[1], w2=wp[2], w3=wp[3];
                    float wv[16] = {w0.x,w0.y,w0.z,w0.w,w1.x,w1.y,w1.z,w1.w,
                                    w2.x,w2.y,w2.z,w2.w,w3.x,w3.y,w3.z,w3.w};
                    #pragma unroll
                    for (int p=0;p<4;++p){
                        float v = win[2*p + kw + 3];
                        #pragma unroll
                        for (int o=0;o<16;++o) acc[o][p] += wv[o]*v;
                    }
                }
            }
        }
        __syncthreads();
    }
    size_t pxbase = (size_t)img*1024 + y*32 + x0;
    #pragma unroll
    for (int p=0;p<4;++p){
        u16x8 h0v, h1v, l0v, l1v;
        #pragma unroll
        for (int o=0;o<8;++o){
            float v0 = acc[o][p];   v0 = LRELU(v0);
            float v1 = acc[o+8][p]; v1 = LRELU(v1);
            unsigned short hh, ll;
            bsplit(v0,hh,ll); h0v[o]=hh; l0v[o]=ll;
            bsplit(v1,hh,ll); h1v[o]=hh; l1v[o]=ll;
        }
        size_t bo = (pxbase + p)*64 + ocBase;
        *(u16x8*)&e2hi[bo]   = h0v; *(u16x8*)&e2hi[bo+8] = h1v;
        *(u16x8*)&e2lo[bo]   = l0v; *(u16x8*)&e2lo[bo+8] = l1v;
    }
}

// ---------------------------------------------------------------------------
// k_prep: pack conv5 weights into MFMA A-fragment order, bf16 hi/lo.
// ---------------------------------------------------------------------------
__global__ __launch_bounds__(256) void k_prep(const float* __restrict__ W,
    int wIcTot, int wIcOff, int icTot, int total,
    unsigned short* __restrict__ outHi, unsigned short* __restrict__ outLo)
{
    int id = blockIdx.x*256 + threadIdx.x;
    if (id >= total) return;
    int lane = id & 63;
    int grp  = id >> 6;
    int ks = grp % 7;
    int rest = grp / 7;
    int iccTot = icTot >> 3;
    int oc = (rest / iccTot)*16 + (lane & 15);
    int t  = ks*4 + (lane >> 4);
    int icBase = (rest % iccTot)*8;
    u16x8 vh, vl;
    #pragma unroll
    for (int r=0;r<8;++r){
        float v = 0.f;
        if (t < 25) v = W[((size_t)oc*wIcTot + wIcOff + icBase + r)*25 + t];
        unsigned short hh, ll; bsplit(v, hh, ll);
        vh[r]=hh; vl[r]=ll;
    }
    size_t base = ((size_t)grp)*512 + lane*8;
    *(u16x8*)&outHi[base] = vh;
    *(u16x8*)&outLo[base] = vl;
}

// ---------------------------------------------------------------------------
// k_prep_d1: pack deconv1 (4x4, lhs_dil 2) weights per parity class.
// ---------------------------------------------------------------------------
__global__ __launch_bounds__(256) void k_prep_d1(const float* __restrict__ W,
    unsigned short* __restrict__ outHi, unsigned short* __restrict__ outLo)
{
    int id = blockIdx.x*256 + threadIdx.x;
    if (id >= 4096) return;
    int lane = id & 63;
    int grp = id >> 6;
    int icc = grp & 7; int par = (grp>>3)&3; int mt = grp>>5;
    int py = par>>1, px = par&1;
    int oc = mt*16 + (lane&15);
    int t = lane>>4; int a = t>>1, bb = t&1;
    int kh = 2*a+py, kw = 2*bb+px;
    u16x8 vh, vl;
    #pragma unroll
    for (int r=0;r<8;++r){
        int ic = icc*8 + r;
        float v = W[(((size_t)oc*64 + ic)*4 + kh)*4 + kw];
        unsigned short hh, ll; bsplit(v, hh, ll);
        vh[r]=hh; vl[r]=ll;
    }
    size_t base = ((size_t)grp)*512 + lane*8;
    *(u16x8*)&outHi[base] = vh;
    *(u16x8*)&outLo[base] = vl;
}

// ---------------------------------------------------------------------------
// k_conv5f: 5x5 pad2 s1 over 32x32, split-bf16 MFMA shift-GEMM, fused GRU
// pointwise epilogue. Double-buffered LDS + register prefetch (T14):
// per icc: barrier -> issue next-icc global loads -> MFMA compute (hides
// latency) -> regs->LDS[other buf]. One barrier per iteration.
// MODE 0 = zr (NOC=4): ocBlk<2 -> r/rh, else z. MODE 1 = cand (NOC=2).
// 1-D grid NOC*(32/ROWS)*32, XCD-aware bijective decode (T1): the NOC
// oc-blocks sharing an input tile run consecutively on one XCD.
// zr now runs ROWS=4 (1024 blocks = 4 blocks/CU) for latency hiding.
// ---------------------------------------------------------------------------
template<int MODE, int ROWS, int NOC>
__global__ __launch_bounds__(256) void k_conv5f(
    const unsigned short* __restrict__ aHi, const unsigned short* __restrict__ aLo,
    unsigned long long strA, int iccA,
    const unsigned short* __restrict__ inbHi, const unsigned short* __restrict__ inbLo,
    unsigned long long strB,
    const unsigned short* __restrict__ wHi, const unsigned short* __restrict__ wLo,
    int iccTot,
    const float* __restrict__ bias,
    const float* __restrict__ h32,
    const float* __restrict__ z32in,
    float* __restrict__ z32out,
    unsigned short* __restrict__ oHi, unsigned short* __restrict__ oLo,
    float* __restrict__ h32out,
    unsigned short* __restrict__ hsHi, unsigned short* __restrict__ hsLo)
{
    constexpr int RW = ROWS/4;          // rows per wave
    constexpr int NT = ROWS/2;          // n-tiles per wave
    constexpr int SPOS = (ROWS+4)*36;
    constexpr int SPAN = (32/ROWS)*4;   // per-XCD (batch,rowtile) span
    __shared__ __align__(16) unsigned short ldsHi[2][SPOS*8];
    __shared__ __align__(16) unsigned short ldsLo[2][SPOS*8];
    int tid = threadIdx.x;
    int lane = tid & 63, wave = tid >> 6;
    int bid = blockIdx.x;
    int m = bid & 7;
    int kk = bid >> 3;
    int ocBlk = kk % NOC;
    int g = kk / NOC;
    int idx = m*SPAN + g;
    int batch = idx & 31;
    int r0 = (idx >> 5)*ROWS;

    // staging geometry (icc-invariant)
    int sA = tid;                       // SPOS >= 288 > 255 -> always valid slot
    int lyA = sA/36, lxA = sA - lyA*36;
    int gyA = r0 - 2 + lyA, gxA = lxA - 2;
    bool vA = (gyA>=0 && gyA<32 && gxA>=0 && gxA<32);
    size_t poA = ((size_t)(gyA*32+gxA))*64;
    int sB = tid + 256;
    bool hasB = (sB < SPOS);
    int lyB = sB/36, lxB = sB - lyB*36;
    int gyB = r0 - 2 + lyB, gxB = lxB - 2;
    bool vB = hasB && (gyB>=0 && gyB<32 && gxB>=0 && gxB<32);
    size_t poB = ((size_t)(gyB*32+gxB))*64;

    int offs[7];
    #pragma unroll
    for (int ks=0; ks<7; ++ks){
        int t = ks*4 + (lane>>4);
        int dy = (t<25)? t/5 : 2;
        int dx = (t<25)? t%5 : 2;
        offs[ks] = (dy*36 + dx)*8;
    }
    int eb[NT];
    #pragma unroll
    for (int n=0;n<NT;++n)
        eb[n] = (((wave*RW + (n>>1))*36) + (n&1)*16 + (lane&15))*8;

    f32x4 acc[2][NT];
    #pragma unroll
    for (int mm=0;mm<2;++mm)
      #pragma unroll
      for (int n=0;n<NT;++n) acc[mm][n] = (f32x4){0.f,0.f,0.f,0.f};

    // prefetch registers (named, no dynamic indexing)
    u16x8 rAh=(u16x8)0, rAl=(u16x8)0, rBh=(u16x8)0, rBl=(u16x8)0;

    // ---- LOAD icc=0 into regs
    {
        const unsigned short* sHp; const unsigned short* sLp; int icLoc;
        if (0 < iccA){ sHp = aHi + (size_t)batch*strA; sLp = aLo + (size_t)batch*strA; icLoc = 0; }
        else         { sHp = inbHi + (size_t)batch*strB; sLp = inbLo + (size_t)batch*strB; icLoc = -iccA; }
        if (vA){ rAh = *(const u16x8*)&sHp[poA + icLoc*8]; rAl = *(const u16x8*)&sLp[poA + icLoc*8]; }
        if (vB){ rBh = *(const u16x8*)&sHp[poB + icLoc*8]; rBl = *(const u16x8*)&sLp[poB + icLoc*8]; }
    }
    // ---- STORE buf0
    *(u16x8*)&ldsHi[0][sA*8] = rAh; *(u16x8*)&ldsLo[0][sA*8] = rAl;
    if (hasB){ *(u16x8*)&ldsHi[0][sB*8] = rBh; *(u16x8*)&ldsLo[0][sB*8] = rBl; }

    int cur = 0;
    for (int icc = 0; icc < iccTot; ++icc){
        __syncthreads();                 // buf[cur] writes visible
        // ---- issue next-icc loads (no wait; consumed after compute)
        if (icc+1 < iccTot){
            int icn = icc+1;
            const unsigned short* sHp; const unsigned short* sLp; int icLoc;
            if (icn < iccA){ sHp = aHi + (size_t)batch*strA; sLp = aLo + (size_t)batch*strA; icLoc = icn; }
            else           { sHp = inbHi + (size_t)batch*strB; sLp = inbLo + (size_t)batch*strB; icLoc = icn - iccA; }
            rAh=(u16x8)0; rAl=(u16x8)0; rBh=(u16x8)0; rBl=(u16x8)0;
            if (vA){ rAh = *(const u16x8*)&sHp[poA + icLoc*8]; rAl = *(const u16x8*)&sLp[poA + icLoc*8]; }
            if (vB){ rBh = *(const u16x8*)&sHp[poB + icLoc*8]; rBl = *(const u16x8*)&sLp[poB + icLoc*8]; }
        }
        // ---- compute on buf[cur]
        const unsigned short* bHp = ldsHi[cur];
        const unsigned short* bLp = ldsLo[cur];
        #pragma unroll
        for (int ks=0; ks<7; ++ks){
            size_t i0 = (((size_t)(ocBlk*2+0)*iccTot + icc)*7 + ks)*512 + lane*8;
            size_t i1 = (((size_t)(ocBlk*2+1)*iccTot + icc)*7 + ks)*512 + lane*8;
            bf16x8 a0h = *(const bf16x8*)&wHi[i0];
            bf16x8 a0l = *(const bf16x8*)&wLo[i0];
            bf16x8 a1h = *(const bf16x8*)&wHi[i1];
            bf16x8 a1l = *(const bf16x8*)&wLo[i1];
            bf16x8 bh[NT], bl[NT];
            #pragma unroll
            for (int n=0;n<NT;++n){
                int e = eb[n] + offs[ks];
                bh[n] = *(const bf16x8*)&bHp[e];
                bl[n] = *(const bf16x8*)&bLp[e];
            }
            #pragma unroll
            for (int n=0;n<NT;++n){
                acc[0][n] = __builtin_amdgcn_mfma_f32_16x16x32_bf16(a0h, bh[n], acc[0][n], 0,0,0);
                acc[0][n] = __builtin_amdgcn_mfma_f32_16x16x32_bf16(a0h, bl[n], acc[0][n], 0,0,0);
                acc[0][n] = __builtin_amdgcn_mfma_f32_16x16x32_bf16(a0l, bh[n], acc[0][n], 0,0,0);
                acc[1][n] = __builtin_amdgcn_mfma_f32_16x16x32_bf16(a1h, bh[n], acc[1][n], 0,0,0);
                acc[1][n] = __builtin_amdgcn_mfma_f32_16x16x32_bf16(a1h, bl[n], acc[1][n], 0,0,0);
                acc[1][n] = __builtin_amdgcn_mfma_f32_16x16x32_bf16(a1l, bh[n], acc[1][n], 0,0,0);
            }
        }
        // ---- write prefetched regs to the other buffer
        if (icc+1 < iccTot){
            int nb = cur ^ 1;
            *(u16x8*)&ldsHi[nb][sA*8] = rAh; *(u16x8*)&ldsLo[nb][sA*8] = rAl;
            if (hasB){ *(u16x8*)&ldsHi[nb][sB*8] = rBh; *(u16x8*)&ldsLo[nb][sB*8] = rBl; }
        }
        cur ^= 1;
    }

    if (MODE == 0){
        bool rside = (ocBlk < 2);
        #pragma unroll
        for (int mm=0;mm<2;++mm){
            int ocBase = ocBlk*32 + mm*16 + (lane>>4)*4;
            f32x4 b4 = *(const f32x4*)&bias[ocBase];
            #pragma unroll
            for (int n=0;n<NT;++n){
                int px = (r0 + wave*RW + (n>>1))*32 + (n&1)*16 + (lane&15);
                if (rside){
                    size_t ii = ((size_t)batch*1024 + px)*64 + ocBase;
                    f32x4 h4 = *(const f32x4*)&h32[ii];
                    u16x4 rH, rL;
                    #pragma unroll
                    for (int j=0;j<4;++j){
                        float r = sigmoidf_(acc[mm][n][j] + b4[j]);
                        unsigned short hh,ll; bsplit(r*h4[j],hh,ll);
                        rH[j]=hh; rL[j]=ll;
                    }
                    *(u16x4*)&oHi[ii] = rH;
                    *(u16x4*)&oLo[ii] = rL;
                } else {
                    size_t ii = ((size_t)batch*1024 + px)*64 + ocBase - 64;
                    f32x4 z;
                    #pragma unroll
                    for (int j=0;j<4;++j) z[j] = sigmoidf_(acc[mm][n][j] + b4[j]);
                    *(f32x4*)&z32out[ii] = z;
                }
            }
        }
    } else {
        #pragma unroll
        for (int mm=0;mm<2;++mm){
            int oc = ocBlk*32 + mm*16 + (lane>>4)*4;
            f32x4 b4 = *(const f32x4*)&bias[oc];
            #pragma unroll
            for (int n=0;n<NT;++n){
                int px = (r0 + wave*RW + (n>>1))*32 + (n&1)*16 + (lane&15);
                size_t ii = ((size_t)batch*1024 + px)*64 + oc;
                f32x4 h4 = *(const f32x4*)&h32[ii];
                f32x4 z4 = *(const f32x4*)&z32in[ii];
                f32x4 hn; u16x4 hh4, hl4;
                #pragma unroll
                for (int j=0;j<4;++j){
                    float c = tanhf(acc[mm][n][j] + b4[j]);
                    hn[j] = (1.f - z4[j])*h4[j] + z4[j]*c;
                    unsigned short hh,ll; bsplit(hn[j],hh,ll);
                    hh4[j]=hh; hl4[j]=ll;
                }
                *(f32x4*)&h32out[ii] = hn;
                *(u16x4*)&oHi[ii] = hh4;
                *(u16x4*)&oLo[ii] = hl4;
                if (hsHi){
                    *(u16x4*)&hsHi[ii] = hh4;
                    *(u16x4*)&hsLo[ii] = hl4;
                }
            }
        }
    }
}

// ---------------------------------------------------------------------------
// k_deconv1m: hs (tb,1024px,64ic bf16 hi/lo) -> y1 (tb,32,64,64) fp32,
// k4 lhs_dil2 pad2 as 4 parity-class 2x2 convs via split-bf16 MFMA.
// Double-buffered staging (T14), XCD-aware decode (T1).
// ---------------------------------------------------------------------------
__global__ __launch_bounds__(256) void k_deconv1m(
    const unsigned short* __restrict__ hsHi, const unsigned short* __restrict__ hsLo,
    const unsigned short* __restrict__ wHi, const unsigned short* __restrict__ wLo,
    const float* __restrict__ Bb, float* __restrict__ y1)
{
    __shared__ __align__(16) unsigned short ldsHi[2][340*8];
    __shared__ __align__(16) unsigned short ldsLo[2][340*8];
    int tid = threadIdx.x;
    int lane = tid & 63, wave = tid >> 6;
    int bid = blockIdx.x;
    int m = bid & 7;
    int kk = bid >> 3;
    int par = kk & 3;
    int g = kk >> 2;
    int idx = m*32 + g;
    int tbl = idx & 63;
    int r0 = (idx >> 6)*8;
    int py = par >> 1, px = par & 1;
    const unsigned short* sH = hsHi + (size_t)tbl*65536;
    const unsigned short* sL = hsLo + (size_t)tbl*65536;

    int sA = tid;
    int lyA = sA/34, lxA = sA - lyA*34;
    int gyA = r0 - 1 + lyA, gxA = lxA - 1;
    bool vA = (gyA>=0 && gyA<32 && gxA>=0 && gxA<32);
    size_t poA = ((size_t)(gyA*32+gxA))*64;
    int sB = tid + 256;
    bool hasB = (sB < 340);
    int lyB = sB/34, lxB = sB - lyB*34;
    int gyB = r0 - 1 + lyB, gxB = lxB - 1;
    bool vB = hasB && (gyB>=0 && gyB<32 && gxB>=0 && gxB<32);
    size_t poB = ((size_t)(gyB*32+gxB))*64;

    int offs0 = ((lane>>5)*34 + ((lane>>4)&1))*8;
    int eb[4];
    #pragma unroll
    for (int n=0;n<4;++n)
        eb[n] = (((wave*2 + (n>>1)) + py)*34 + (n&1)*16 + (lane&15) + px)*8;

    f32x4 acc[2][4];
    #pragma unroll
    for (int mm=0;mm<2;++mm)
      #pragma unroll
      for (int n=0;n<4;++n) acc[mm][n] = (f32x4){0.f,0.f,0.f,0.f};

    u16x8 rAh=(u16x8)0, rAl=(u16x8)0, rBh=(u16x8)0, rBl=(u16x8)0;
    if (vA){ rAh = *(const u16x8*)&sH[poA]; rAl = *(const u16x8*)&sL[poA]; }
    if (vB){ rBh = *(const u16x8*)&sH[poB]; rBl = *(const u16x8*)&sL[poB]; }
    *(u16x8*)&ldsHi[0][sA*8] = rAh; *(u16x8*)&ldsLo[0][sA*8] = rAl;
    if (hasB){ *(u16x8*)&ldsHi[0][sB*8] = rBh; *(u16x8*)&ldsLo[0][sB*8] = rBl; }

    int cur = 0;
    for (int icc=0; icc<8; ++icc){
        __syncthreads();
        if (icc+1 < 8){
            size_t co = (size_t)(icc+1)*8;
            rAh=(u16x8)0; rAl=(u16x8)0; rBh=(u16x8)0; rBl=(u16x8)0;
            if (vA){ rAh = *(const u16x8*)&sH[poA + co]; rAl = *(const u16x8*)&sL[poA + co]; }
            if (vB){ rBh = *(const u16x8*)&sH[poB + co]; rBl = *(const u16x8*)&sL[poB + co]; }
        }
        const unsigned short* bHp = ldsHi[cur];
        const unsigned short* bLp = ldsLo[cur];
        size_t i0 = ((size_t)((0*4 + par)*8 + icc))*512 + lane*8;
        size_t i1 = ((size_t)((1*4 + par)*8 + icc))*512 + lane*8;
        bf16x8 a0h = *(const bf16x8*)&wHi[i0];
        bf16x8 a0l = *(const bf16x8*)&wLo[i0];
        bf16x8 a1h = *(const bf16x8*)&wHi[i1];
        bf16x8 a1l = *(const bf16x8*)&wLo[i1];
        bf16x8 bh[4], bl[4];
        #pragma unroll
        for (int n=0;n<4;++n){
            int e = eb[n] + offs0;
            bh[n] = *(const bf16x8*)&bHp[e];
            bl[n] = *(const bf16x8*)&bLp[e];
        }
        #pragma unroll
        for (int n=0;n<4;++n){
            acc[0][n] = __builtin_amdgcn_mfma_f32_16x16x32_bf16(a0h, bh[n], acc[0][n], 0,0,0);
            acc[0][n] = __builtin_amdgcn_mfma_f32_16x16x32_bf16(a0h, bl[n], acc[0][n], 0,0,0);
            acc[0][n] = __builtin_amdgcn_mfma_f32_16x16x32_bf16(a0l, bh[n], acc[0][n], 0,0,0);
            acc[1][n] = __builtin_amdgcn_mfma_f32_16x16x32_bf16(a1h, bh[n], acc[1][n], 0,0,0);
            acc[1][n] = __builtin_amdgcn_mfma_f32_16x16x32_bf16(a1h, bl[n], acc[1][n], 0,0,0);
            acc[1][n] = __builtin_amdgcn_mfma_f32_16x16x32_bf16(a1l, bh[n], acc[1][n], 0,0,0);
        }
        if (icc+1 < 8){
            int nb = cur ^ 1;
            *(u16x8*)&ldsHi[nb][sA*8] = rAh; *(u16x8*)&ldsLo[nb][sA*8] = rAl;
            if (hasB){ *(u16x8*)&ldsHi[nb][sB*8] = rBh; *(u16x8*)&ldsLo[nb][sB*8] = rBl; }
        }
        cur ^= 1;
    }
    #pragma unroll
    for (int mm=0;mm<2;++mm){
        int ocb = mm*16 + (lane>>4)*4;
        #pragma unroll
        for (int n=0;n<4;++n){
            int oyr = r0 + wave*2 + (n>>1);
            int oxc = (n&1)*16 + (lane&15);
            int oy = 2*oyr + py, ox = 2*oxc + px;
            float* dst = y1 + ((size_t)tbl*32 + ocb)*4096 + oy*64 + ox;
            #pragma unroll
            for (int j=0;j<4;++j){
                float v = acc[mm][n][j] + Bb[ocb+j];
                dst[(size_t)j*4096] = LRELU(v);
            }
        }
    }
}

// ---------------------------------------------------------------------------
// deconv2: y1 (Ntb,32,64,64) -> out with (t,b) permute, k4 lhs_dil2 pad2, bias.
// ---------------------------------------------------------------------------
__global__ __launch_bounds__(256) void k_deconv2(const float* __restrict__ in,
    const float* __restrict__ W, const float* __restrict__ Bb, float* __restrict__ out,
    int tbOff)
{
    __shared__ float wl[512];
    int tid = threadIdx.x;
    for (int e=tid; e<512; e+=256) wl[e] = W[e];   // [ic][kh][kw], oc=1
    __syncthreads();
    int tbl = blockIdx.y;
    int tb = tbOff + tbl; int t = tb >> 5; int b = tb & 31;
    int idx4 = blockIdx.x*256 + tid;
    int oy = idx4 >> 5; int ox0 = (idx4 & 31)*4;
    int ph = oy & 1;
    const float* base = in + (size_t)tbl*131072;
    float acc0=0.f, acc1=0.f, acc2=0.f, acc3=0.f;
    int ix0 = ox0/2 - 1;
    for (int ic=0; ic<32; ++ic){
        const float* cp = base + ic*4096;
        #pragma unroll
        for (int kk=0; kk<2; ++kk){
            int kh = ph + 2*kk;
            int iy = (oy + kh - 2) >> 1;
            if (iy < 0 || iy > 63) continue;
            const float* rp = cp + (size_t)iy*64;
            float wv0 = (ix0 >= 0)   ? rp[ix0]   : 0.f;
            float wv1 = rp[ix0+1];
            float wv2 = rp[ix0+2];
            float wv3 = (ix0+3 <= 63) ? rp[ix0+3] : 0.f;
            float w0 = wl[ic*16 + kh*4 + 0];
            float w1 = wl[ic*16 + kh*4 + 1];
            float w2 = wl[ic*16 + kh*4 + 2];
            float w3 = wl[ic*16 + kh*4 + 3];
            acc0 += w0*wv0 + w2*wv1;        // p=0: kw 0,2
            acc2 += w0*wv1 + w2*wv2;        // p=2
            acc1 += w1*wv1 + w3*wv2;        // p=1: kw 1,3
            acc3 += w1*wv2 + w3*wv3;        // p=3
        }
    }
    float bv = Bb[0];
    float4 res = make_float4(acc0+bv, acc1+bv, acc2+bv, acc3+bv);
    float* op = out + ((size_t)(b*10 + t))*16384 + (size_t)oy*128 + ox0;
    *(float4*)op = res;
}

// ---------------------------------------------------------------------------
// Workspace (bytes), peak 121,700,352 — layout identical to rounds 5-7.
// ---------------------------------------------------------------------------
extern "C" void kernel_launch(void* const* d_in, const int* in_sizes, int n_in,
                              void* d_out, int out_size, void* d_ws, size_t ws_size,
                              hipStream_t stream)
{
    const float* x    = (const float*)d_in[0];
    const float* ew1  = (const float*)d_in[1];
    const float* eb1  = (const float*)d_in[2];
    const float* ew2  = (const float*)d_in[3];
    const float* eb2  = (const float*)d_in[4];
    const float* ewzr = (const float*)d_in[5];
    const float* ebzr = (const float*)d_in[6];
    const float* ewc  = (const float*)d_in[7];
    const float* ebc  = (const float*)d_in[8];
    const float* dwzr = (const float*)d_in[9];
    const float* dbzr = (const float*)d_in[10];
    const float* dwc  = (const float*)d_in[11];
    const float* dbc  = (const float*)d_in[12];
    const float* dw1  = (const float*)d_in[13];
    const float* db1  = (const float*)d_in[14];
    const float* dw2  = (const float*)d_in[15];
    const float* db2  = (const float*)d_in[16];
    float* out = (float*)d_out;
    char* ws = (char*)d_ws;

    unsigned short* e2hi = (unsigned short*)(ws + 0);
    unsigned short* e2lo = (unsigned short*)(ws + 41943040UL);
    float*          h32  = (float*)(ws + 83886080UL);
    unsigned short* hHi  = (unsigned short*)(ws + 92274688UL);
    unsigned short* hLo  = (unsigned short*)(ws + 96468992UL);
    unsigned short* rhHi = (unsigned short*)(ws + 100663296UL);
    unsigned short* rhLo = (unsigned short*)(ws + 104857600UL);
    float*          z32  = (float*)(ws + 109051904UL);
    unsigned short* A0   = (unsigned short*)(ws + 117440512UL);
    unsigned short* AzrH = A0;            unsigned short* AzrL = A0 + 458752;
    unsigned short* AcH  = A0 + 917504;   unsigned short* AcL  = A0 + 1146880;
    unsigned short* DzrH = A0 + 1376256;  unsigned short* DzrL = A0 + 1605632;
    unsigned short* DcH  = A0 + 1835008;  unsigned short* DcL  = A0 + 1949696;
    unsigned short* D1H  = A0 + 2064384;  unsigned short* D1L  = A0 + 2097152;
    float* e1c = (float*)(ws + 83886080UL);   // phase-1 overlay (40 MB)
    float* y1c = (float*)(ws + 83886080UL);   // phase-4 overlay (33.5 MB)

    // Phase 1: conv1 -> conv2 (e2 split channel-last), chunked x2
    for (int c=0; c<2; ++c){
        int off = c*160;
        k_conv1<<<dim3(16,160),256,0,stream>>>(x + (size_t)off*16384, ew1, eb1, e1c);
        k_conv2<<<dim3(4,160),256,0,stream>>>(e1c, ew2, eb2,
                                              e2hi + (size_t)off*65536,
                                              e2lo + (size_t)off*65536);
    }

    // Weight packing AFTER phase 1 (e1c overlay covers the pack region)
    k_prep<<<224,256,0,stream>>>(ewzr, 128, 0, 128, 57344, AzrH, AzrL);
    k_prep<<<112,256,0,stream>>>(ewc,  128, 0, 128, 28672, AcH,  AcL);
    k_prep<<<112,256,0,stream>>>(dwzr, 128, 64, 64, 28672, DzrH, DzrL);
    k_prep<<< 56,256,0,stream>>>(dwc,  128, 64, 64, 14336, DcH,  DcL);
    k_prep_d1<<<16,256,0,stream>>>(dw1, D1H, D1L);

    hipMemsetAsync(h32, 0, 8388608UL, stream);
    hipMemsetAsync(hHi, 0, 4194304UL, stream);
    hipMemsetAsync(hLo, 0, 4194304UL, stream);

    // Phase 2: encoder GRU scan (zr now ROWS=4 -> 1024 blocks = 4/CU)
    for (int t=0; t<10; ++t){
        k_conv5f<0,4,4><<<1024,256,0,stream>>>(
            e2hi + (size_t)t*65536, e2lo + (size_t)t*65536, 655360ULL, 8,
            hHi, hLo, 65536ULL, AzrH, AzrL, 16, ebzr,
            h32, nullptr, z32, rhHi, rhLo, nullptr, nullptr, nullptr);
        k_conv5f<1,4,2><<<512,256,0,stream>>>(
            e2hi + (size_t)t*65536, e2lo + (size_t)t*65536, 655360ULL, 8,
            rhHi, rhLo, 65536ULL, AcH, AcL, 16, ebc,
            h32, z32, nullptr, hHi, hLo, h32, nullptr, nullptr);
    }
    // Phase 3: decoder GRU scan; hs (bf16 hi/lo) overlays e2
    for (int t=0; t<10; ++t){
        k_conv5f<0,4,4><<<1024,256,0,stream>>>(
            hHi, hLo, 65536ULL, 8,
            hHi, hLo, 65536ULL, DzrH, DzrL, 8, dbzr,
            h32, nullptr, z32, rhHi, rhLo, nullptr, nullptr, nullptr);
        k_conv5f<1,4,2><<<512,256,0,stream>>>(
            rhHi, rhLo, 65536ULL, 8,
            rhHi, rhLo, 65536ULL, DcH, DcL, 8, dbc,
            h32, z32, nullptr, hHi, hLo, h32,
            e2hi + (size_t)t*2097152, e2lo + (size_t)t*2097152);
    }
    // Phase 4: deconv1m (MFMA) -> deconv2, chunked x5 over tb (64 each)
    for (int c=0; c<5; ++c){
        int tbOff = c*64;
        k_deconv1m<<<1024,256,0,stream>>>(
            e2hi + (size_t)tbOff*65536, e2lo + (size_t)tbOff*65536,
            D1H, D1L, db1, y1c);
        k_deconv2<<<dim3(16,64),256,0,stream>>>(y1c, dw2, db2, out, tbOff);
    }
}

// Round 10
// 2949.126 us; speedup vs baseline: 1.0075x; 1.0075x over previous
//
#include <hip/hip_runtime.h>
#include <math.h>

#define LRELU(v) ((v) >= 0.f ? (v) : 0.2f*(v))

__device__ __forceinline__ float sigmoidf_(float x){ return 1.f/(1.f + expf(-x)); }

typedef __attribute__((ext_vector_type(8))) short bf16x8;
typedef __attribute__((ext_vector_type(4))) float f32x4;
typedef __attribute__((ext_vector_type(8))) unsigned short u16x8;
typedef __attribute__((ext_vector_type(4))) unsigned short u16x4;

__device__ __forceinline__ unsigned short bf16_rne(float x){
    union { float f; unsigned u; } v; v.f = x;
    unsigned r = v.u + 0x7fffu + ((v.u >> 16) & 1u);
    return (unsigned short)(r >> 16);
}
__device__ __forceinline__ float bf16_tof(unsigned short h){
    union { float f; unsigned u; } v; v.u = ((unsigned)h) << 16; return v.f;
}
__device__ __forceinline__ void bsplit(float x, unsigned short& hi, unsigned short& lo){
    hi = bf16_rne(x);
    lo = bf16_rne(x - bf16_tof(hi));
}

// ---------------------------------------------------------------------------
// conv1: x (Nimg,1,128,128) -> e1 (Nimg,16,64,64) fp32 ch-first, k3 s2 p1.
// ---------------------------------------------------------------------------
__global__ __launch_bounds__(256) void k_conv1(const float* __restrict__ x,
    const float* __restrict__ W, const float* __restrict__ Bb, float* __restrict__ out)
{
    __shared__ float wl[144];
    __shared__ float bl[16];
    int tid = threadIdx.x;
    if (tid < 144) { int oc = tid/9, tap = tid%9; wl[tap*16+oc] = W[oc*9+tap]; }
    if (tid < 16) bl[tid] = Bb[tid];
    __syncthreads();
    int img = blockIdx.y;
    int px = blockIdx.x*256 + tid;
    int oy = px >> 6, ox = px & 63;
    const float* xin = x + (size_t)img*16384;
    float acc[16];
    #pragma unroll
    for (int o=0;o<16;++o) acc[o]=bl[o];
    #pragma unroll
    for (int kh=0; kh<3; ++kh){
        int iy = 2*oy + kh - 1;
        bool vy = (iy>=0 && iy<128);
        #pragma unroll
        for (int kw=0; kw<3; ++kw){
            int ix = 2*ox + kw - 1;
            float v = (vy && ix>=0 && ix<128) ? xin[iy*128+ix] : 0.f;
            int tap = kh*3+kw;
            #pragma unroll
            for (int o=0;o<16;++o) acc[o] += wl[tap*16+o]*v;
        }
    }
    float* op = out + (size_t)img*65536 + px;
    #pragma unroll
    for (int o=0;o<16;++o){ float v = acc[o]; op[o*4096] = LRELU(v); }
}

// ---------------------------------------------------------------------------
// conv2: e1 (Nimg,16,64,64) -> e2 split bf16 hi/lo CHANNEL-LAST [img][1024][64]
// ---------------------------------------------------------------------------
__global__ __launch_bounds__(256) void k_conv2(const float* __restrict__ in,
    const float* __restrict__ W, const float* __restrict__ Bb,
    unsigned short* __restrict__ e2hi, unsigned short* __restrict__ e2lo)
{
    __shared__ float tile[2*65*68];
    __shared__ float wl[2*9*16];
    int tid = threadIdx.x;
    int img = blockIdx.y;
    int ocBase = blockIdx.x*16;
    int y = tid >> 3, xg = tid & 7, x0 = xg*4;
    float acc[16][4];
    #pragma unroll
    for (int o=0;o<16;++o){ float b = Bb[ocBase+o];
        #pragma unroll
        for (int p=0;p<4;++p) acc[o][p] = b; }
    const float* base = in + (size_t)img*65536;
    for (int icB=0; icB<16; icB+=2){
        for (int e=tid; e<2210; e+=256){            // 2*65*17 float4
            int c4 = e % 17; int rr = (e/17)%65; int ch = e/(17*65);
            int iy = rr - 1; int ixb = c4*4 - 4;
            float4 v = make_float4(0.f,0.f,0.f,0.f);
            if (iy>=0 && iy<64 && c4>=1)
                v = *(const float4*)(base + (icB+ch)*4096 + iy*64 + ixb);
            *(float4*)(&tile[ch*4420 + rr*68 + c4*4]) = v;
        }
        for (int e=tid; e<288; e+=256){
            int oc = e & 15; int rest = e >> 4; int tap = rest % 9; int ch = rest/9;
            wl[(ch*9+tap)*16 + oc] = W[((ocBase+oc)*16 + icB+ch)*9 + tap];
        }
        __syncthreads();
        #pragma unroll
        for (int ch=0; ch<2; ++ch){
            #pragma unroll
            for (int kh=0; kh<3; ++kh){
                int r = 2*y + kh;
                const float4* row = (const float4*)(&tile[ch*4420 + r*68 + 2*x0]);
                float4 a0=row[0], a1=row[1], a2=row[2];
                float win[12] = {a0.x,a0.y,a0.z,a0.w,a1.x,a1.y,a1.z,a1.w,a2.x,a2.y,a2.z,a2.w};
                #pragma unroll
                for (int kw=0; kw<3; ++kw){
                    const float4* wp = (const float4*)(&wl[(ch*9+kh*3+kw)*16]);
                    float4 w0=wp[0], w1=wp[1], w2=wp[2], w3=wp[3];
                    float wv[16] = {w0.x,w0.y,w0.z,w0.w,w1.x,w1.y,w1.z,w1.w,
                                    w2.x,w2.y,w2.z,w2.w,w3.x,w3.y,w3.z,w3.w};
                    #pragma unroll
                    for (int p=0;p<4;++p){
                        float v = win[2*p + kw + 3];
                        #pragma unroll
                        for (int o=0;o<16;++o) acc[o][p] += wv[o]*v;
                    }
                }
            }
        }
        __syncthreads();
    }
    size_t pxbase = (size_t)img*1024 + y*32 + x0;
    #pragma unroll
    for (int p=0;p<4;++p){
        u16x8 h0v, h1v, l0v, l1v;
        #pragma unroll
        for (int o=0;o<8;++o){
            float v0 = acc[o][p];   v0 = LRELU(v0);
            float v1 = acc[o+8][p]; v1 = LRELU(v1);
            unsigned short hh, ll;
            bsplit(v0,hh,ll); h0v[o]=hh; l0v[o]=ll;
            bsplit(v1,hh,ll); h1v[o]=hh; l1v[o]=ll;
        }
        size_t bo = (pxbase + p)*64 + ocBase;
        *(u16x8*)&e2hi[bo]   = h0v; *(u16x8*)&e2hi[bo+8] = h1v;
        *(u16x8*)&e2lo[bo]   = l0v; *(u16x8*)&e2lo[bo+8] = l1v;
    }
}

// ---------------------------------------------------------------------------
// k_prep: pack conv5 weights into MFMA A-fragment order, bf16 hi/lo.
// ---------------------------------------------------------------------------
__global__ __launch_bounds__(256) void k_prep(const float* __restrict__ W,
    int wIcTot, int wIcOff, int icTot, int total,
    unsigned short* __restrict__ outHi, unsigned short* __restrict__ outLo)
{
    int id = blockIdx.x*256 + threadIdx.x;
    if (id >= total) return;
    int lane = id & 63;
    int grp  = id >> 6;
    int ks = grp % 7;
    int rest = grp / 7;
    int iccTot = icTot >> 3;
    int oc = (rest / iccTot)*16 + (lane & 15);
    int t  = ks*4 + (lane >> 4);
    int icBase = (rest % iccTot)*8;
    u16x8 vh, vl;
    #pragma unroll
    for (int r=0;r<8;++r){
        float v = 0.f;
        if (t < 25) v = W[((size_t)oc*wIcTot + wIcOff + icBase + r)*25 + t];
        unsigned short hh, ll; bsplit(v, hh, ll);
        vh[r]=hh; vl[r]=ll;
    }
    size_t base = ((size_t)grp)*512 + lane*8;
    *(u16x8*)&outHi[base] = vh;
    *(u16x8*)&outLo[base] = vl;
}

// ---------------------------------------------------------------------------
// k_prep_d1: pack deconv1 (4x4, lhs_dil 2) weights per parity class.
// ---------------------------------------------------------------------------
__global__ __launch_bounds__(256) void k_prep_d1(const float* __restrict__ W,
    unsigned short* __restrict__ outHi, unsigned short* __restrict__ outLo)
{
    int id = blockIdx.x*256 + threadIdx.x;
    if (id >= 4096) return;
    int lane = id & 63;
    int grp = id >> 6;
    int icc = grp & 7; int par = (grp>>3)&3; int mt = grp>>5;
    int py = par>>1, px = par&1;
    int oc = mt*16 + (lane&15);
    int t = lane>>4; int a = t>>1, bb = t&1;
    int kh = 2*a+py, kw = 2*bb+px;
    u16x8 vh, vl;
    #pragma unroll
    for (int r=0;r<8;++r){
        int ic = icc*8 + r;
        float v = W[(((size_t)oc*64 + ic)*4 + kh)*4 + kw];
        unsigned short hh, ll; bsplit(v, hh, ll);
        vh[r]=hh; vl[r]=ll;
    }
    size_t base = ((size_t)grp)*512 + lane*8;
    *(u16x8*)&outHi[base] = vh;
    *(u16x8*)&outLo[base] = vl;
}

// ---------------------------------------------------------------------------
// k_conv5f: 5x5 pad2 s1 over 32x32, split-bf16 MFMA shift-GEMM, fused GRU
// pointwise epilogue. Double-buffered LDS input (T14) + BULK per-icc weight
// hoist: all 28 weight fragments (7 ks x 2 oc-tiles x hi/lo) loaded into
// registers before the MFMA section, so L2 latency is pipelined instead of
// exposed per-ks. zr back at ROWS=8 (NT=4: 2x better weight amortization
// than ROWS=4 — round-9 lesson).
// ---------------------------------------------------------------------------
template<int MODE, int ROWS, int NOC>
__global__ __launch_bounds__(256) void k_conv5f(
    const unsigned short* __restrict__ aHi, const unsigned short* __restrict__ aLo,
    unsigned long long strA, int iccA,
    const unsigned short* __restrict__ inbHi, const unsigned short* __restrict__ inbLo,
    unsigned long long strB,
    const unsigned short* __restrict__ wHi, const unsigned short* __restrict__ wLo,
    int iccTot,
    const float* __restrict__ bias,
    const float* __restrict__ h32,
    const float* __restrict__ z32in,
    float* __restrict__ z32out,
    unsigned short* __restrict__ oHi, unsigned short* __restrict__ oLo,
    float* __restrict__ h32out,
    unsigned short* __restrict__ hsHi, unsigned short* __restrict__ hsLo)
{
    constexpr int RW = ROWS/4;          // rows per wave
    constexpr int NT = ROWS/2;          // n-tiles per wave
    constexpr int SPOS = (ROWS+4)*36;
    constexpr int SPAN = (32/ROWS)*4;   // per-XCD (batch,rowtile) span
    __shared__ __align__(16) unsigned short ldsHi[2][SPOS*8];
    __shared__ __align__(16) unsigned short ldsLo[2][SPOS*8];
    int tid = threadIdx.x;
    int lane = tid & 63, wave = tid >> 6;
    int bid = blockIdx.x;
    int m = bid & 7;
    int kk = bid >> 3;
    int ocBlk = kk % NOC;
    int g = kk / NOC;
    int idx = m*SPAN + g;
    int batch = idx & 31;
    int r0 = (idx >> 5)*ROWS;

    // staging geometry (icc-invariant)
    int sA = tid;                       // SPOS >= 288 > 255 -> always valid slot
    int lyA = sA/36, lxA = sA - lyA*36;
    int gyA = r0 - 2 + lyA, gxA = lxA - 2;
    bool vA = (gyA>=0 && gyA<32 && gxA>=0 && gxA<32);
    size_t poA = ((size_t)(gyA*32+gxA))*64;
    int sB = tid + 256;
    bool hasB = (sB < SPOS);
    int lyB = sB/36, lxB = sB - lyB*36;
    int gyB = r0 - 2 + lyB, gxB = lxB - 2;
    bool vB = hasB && (gyB>=0 && gyB<32 && gxB>=0 && gxB<32);
    size_t poB = ((size_t)(gyB*32+gxB))*64;

    int offs[7];
    #pragma unroll
    for (int ks=0; ks<7; ++ks){
        int t = ks*4 + (lane>>4);
        int dy = (t<25)? t/5 : 2;
        int dx = (t<25)? t%5 : 2;
        offs[ks] = (dy*36 + dx)*8;
    }
    int eb[NT];
    #pragma unroll
    for (int n=0;n<NT;++n)
        eb[n] = (((wave*RW + (n>>1))*36) + (n&1)*16 + (lane&15))*8;

    f32x4 acc[2][NT];
    #pragma unroll
    for (int mm=0;mm<2;++mm)
      #pragma unroll
      for (int n=0;n<NT;++n) acc[mm][n] = (f32x4){0.f,0.f,0.f,0.f};

    // prefetch registers (named, no dynamic indexing)
    u16x8 rAh=(u16x8)0, rAl=(u16x8)0, rBh=(u16x8)0, rBl=(u16x8)0;

    // ---- LOAD icc=0 into regs
    {
        const unsigned short* sHp; const unsigned short* sLp; int icLoc;
        if (0 < iccA){ sHp = aHi + (size_t)batch*strA; sLp = aLo + (size_t)batch*strA; icLoc = 0; }
        else         { sHp = inbHi + (size_t)batch*strB; sLp = inbLo + (size_t)batch*strB; icLoc = -iccA; }
        if (vA){ rAh = *(const u16x8*)&sHp[poA + icLoc*8]; rAl = *(const u16x8*)&sLp[poA + icLoc*8]; }
        if (vB){ rBh = *(const u16x8*)&sHp[poB + icLoc*8]; rBl = *(const u16x8*)&sLp[poB + icLoc*8]; }
    }
    // ---- STORE buf0
    *(u16x8*)&ldsHi[0][sA*8] = rAh; *(u16x8*)&ldsLo[0][sA*8] = rAl;
    if (hasB){ *(u16x8*)&ldsHi[0][sB*8] = rBh; *(u16x8*)&ldsLo[0][sB*8] = rBl; }

    int cur = 0;
    for (int icc = 0; icc < iccTot; ++icc){
        __syncthreads();                 // buf[cur] writes visible
        // ---- issue next-icc input loads (deepest latency; no wait)
        if (icc+1 < iccTot){
            int icn = icc+1;
            const unsigned short* sHp; const unsigned short* sLp; int icLoc;
            if (icn < iccA){ sHp = aHi + (size_t)batch*strA; sLp = aLo + (size_t)batch*strA; icLoc = icn; }
            else           { sHp = inbHi + (size_t)batch*strB; sLp = inbLo + (size_t)batch*strB; icLoc = icn - iccA; }
            rAh=(u16x8)0; rAl=(u16x8)0; rBh=(u16x8)0; rBl=(u16x8)0;
            if (vA){ rAh = *(const u16x8*)&sHp[poA + icLoc*8]; rAl = *(const u16x8*)&sLp[poA + icLoc*8]; }
            if (vB){ rBh = *(const u16x8*)&sHp[poB + icLoc*8]; rBl = *(const u16x8*)&sLp[poB + icLoc*8]; }
        }
        // ---- bulk weight hoist: all 28 fragments for this icc (L2 pipelined)
        bf16x8 wv[28];
        #pragma unroll
        for (int ks=0; ks<7; ++ks){
            size_t i0 = (((size_t)(ocBlk*2+0)*iccTot + icc)*7 + ks)*512 + lane*8;
            size_t i1 = (((size_t)(ocBlk*2+1)*iccTot + icc)*7 + ks)*512 + lane*8;
            wv[ks*4+0] = *(const bf16x8*)&wHi[i0];
            wv[ks*4+1] = *(const bf16x8*)&wLo[i0];
            wv[ks*4+2] = *(const bf16x8*)&wHi[i1];
            wv[ks*4+3] = *(const bf16x8*)&wLo[i1];
        }
        // ---- compute on buf[cur]
        const unsigned short* bHp = ldsHi[cur];
        const unsigned short* bLp = ldsLo[cur];
        #pragma unroll
        for (int ks=0; ks<7; ++ks){
            bf16x8 a0h = wv[ks*4+0];
            bf16x8 a0l = wv[ks*4+1];
            bf16x8 a1h = wv[ks*4+2];
            bf16x8 a1l = wv[ks*4+3];
            bf16x8 bh[NT], bl[NT];
            #pragma unroll
            for (int n=0;n<NT;++n){
                int e = eb[n] + offs[ks];
                bh[n] = *(const bf16x8*)&bHp[e];
                bl[n] = *(const bf16x8*)&bLp[e];
            }
            #pragma unroll
            for (int n=0;n<NT;++n){
                acc[0][n] = __builtin_amdgcn_mfma_f32_16x16x32_bf16(a0h, bh[n], acc[0][n], 0,0,0);
                acc[0][n] = __builtin_amdgcn_mfma_f32_16x16x32_bf16(a0h, bl[n], acc[0][n], 0,0,0);
                acc[0][n] = __builtin_amdgcn_mfma_f32_16x16x32_bf16(a0l, bh[n], acc[0][n], 0,0,0);
                acc[1][n] = __builtin_amdgcn_mfma_f32_16x16x32_bf16(a1h, bh[n], acc[1][n], 0,0,0);
                acc[1][n] = __builtin_amdgcn_mfma_f32_16x16x32_bf16(a1h, bl[n], acc[1][n], 0,0,0);
                acc[1][n] = __builtin_amdgcn_mfma_f32_16x16x32_bf16(a1l, bh[n], acc[1][n], 0,0,0);
            }
        }
        // ---- write prefetched input regs to the other buffer
        if (icc+1 < iccTot){
            int nb = cur ^ 1;
            *(u16x8*)&ldsHi[nb][sA*8] = rAh; *(u16x8*)&ldsLo[nb][sA*8] = rAl;
            if (hasB){ *(u16x8*)&ldsHi[nb][sB*8] = rBh; *(u16x8*)&ldsLo[nb][sB*8] = rBl; }
        }
        cur ^= 1;
    }

    if (MODE == 0){
        bool rside = (ocBlk < 2);
        #pragma unroll
        for (int mm=0;mm<2;++mm){
            int ocBase = ocBlk*32 + mm*16 + (lane>>4)*4;
            f32x4 b4 = *(const f32x4*)&bias[ocBase];
            #pragma unroll
            for (int n=0;n<NT;++n){
                int px = (r0 + wave*RW + (n>>1))*32 + (n&1)*16 + (lane&15);
                if (rside){
                    size_t ii = ((size_t)batch*1024 + px)*64 + ocBase;
                    f32x4 h4 = *(const f32x4*)&h32[ii];
                    u16x4 rH, rL;
                    #pragma unroll
                    for (int j=0;j<4;++j){
                        float r = sigmoidf_(acc[mm][n][j] + b4[j]);
                        unsigned short hh,ll; bsplit(r*h4[j],hh,ll);
                        rH[j]=hh; rL[j]=ll;
                    }
                    *(u16x4*)&oHi[ii] = rH;
                    *(u16x4*)&oLo[ii] = rL;
                } else {
                    size_t ii = ((size_t)batch*1024 + px)*64 + ocBase - 64;
                    f32x4 z;
                    #pragma unroll
                    for (int j=0;j<4;++j) z[j] = sigmoidf_(acc[mm][n][j] + b4[j]);
                    *(f32x4*)&z32out[ii] = z;
                }
            }
        }
    } else {
        #pragma unroll
        for (int mm=0;mm<2;++mm){
            int oc = ocBlk*32 + mm*16 + (lane>>4)*4;
            f32x4 b4 = *(const f32x4*)&bias[oc];
            #pragma unroll
            for (int n=0;n<NT;++n){
                int px = (r0 + wave*RW + (n>>1))*32 + (n&1)*16 + (lane&15);
                size_t ii = ((size_t)batch*1024 + px)*64 + oc;
                f32x4 h4 = *(const f32x4*)&h32[ii];
                f32x4 z4 = *(const f32x4*)&z32in[ii];
                f32x4 hn; u16x4 hh4, hl4;
                #pragma unroll
                for (int j=0;j<4;++j){
                    float c = tanhf(acc[mm][n][j] + b4[j]);
                    hn[j] = (1.f - z4[j])*h4[j] + z4[j]*c;
                    unsigned short hh,ll; bsplit(hn[j],hh,ll);
                    hh4[j]=hh; hl4[j]=ll;
                }
                *(f32x4*)&h32out[ii] = hn;
                *(u16x4*)&oHi[ii] = hh4;
                *(u16x4*)&oLo[ii] = hl4;
                if (hsHi){
                    *(u16x4*)&hsHi[ii] = hh4;
                    *(u16x4*)&hsLo[ii] = hl4;
                }
            }
        }
    }
}

// ---------------------------------------------------------------------------
// k_deconv1m: hs (tb,1024px,64ic bf16 hi/lo) -> y1 (tb,32,64,64) fp32,
// k4 lhs_dil2 pad2 as 4 parity-class 2x2 convs via split-bf16 MFMA.
// Double-buffered staging (T14), XCD-aware decode (T1).
// ---------------------------------------------------------------------------
__global__ __launch_bounds__(256) void k_deconv1m(
    const unsigned short* __restrict__ hsHi, const unsigned short* __restrict__ hsLo,
    const unsigned short* __restrict__ wHi, const unsigned short* __restrict__ wLo,
    const float* __restrict__ Bb, float* __restrict__ y1)
{
    __shared__ __align__(16) unsigned short ldsHi[2][340*8];
    __shared__ __align__(16) unsigned short ldsLo[2][340*8];
    int tid = threadIdx.x;
    int lane = tid & 63, wave = tid >> 6;
    int bid = blockIdx.x;
    int m = bid & 7;
    int kk = bid >> 3;
    int par = kk & 3;
    int g = kk >> 2;
    int idx = m*32 + g;
    int tbl = idx & 63;
    int r0 = (idx >> 6)*8;
    int py = par >> 1, px = par & 1;
    const unsigned short* sH = hsHi + (size_t)tbl*65536;
    const unsigned short* sL = hsLo + (size_t)tbl*65536;

    int sA = tid;
    int lyA = sA/34, lxA = sA - lyA*34;
    int gyA = r0 - 1 + lyA, gxA = lxA - 1;
    bool vA = (gyA>=0 && gyA<32 && gxA>=0 && gxA<32);
    size_t poA = ((size_t)(gyA*32+gxA))*64;
    int sB = tid + 256;
    bool hasB = (sB < 340);
    int lyB = sB/34, lxB = sB - lyB*34;
    int gyB = r0 - 1 + lyB, gxB = lxB - 1;
    bool vB = hasB && (gyB>=0 && gyB<32 && gxB>=0 && gxB<32);
    size_t poB = ((size_t)(gyB*32+gxB))*64;

    int offs0 = ((lane>>5)*34 + ((lane>>4)&1))*8;
    int eb[4];
    #pragma unroll
    for (int n=0;n<4;++n)
        eb[n] = (((wave*2 + (n>>1)) + py)*34 + (n&1)*16 + (lane&15) + px)*8;

    f32x4 acc[2][4];
    #pragma unroll
    for (int mm=0;mm<2;++mm)
      #pragma unroll
      for (int n=0;n<4;++n) acc[mm][n] = (f32x4){0.f,0.f,0.f,0.f};

    u16x8 rAh=(u16x8)0, rAl=(u16x8)0, rBh=(u16x8)0, rBl=(u16x8)0;
    if (vA){ rAh = *(const u16x8*)&sH[poA]; rAl = *(const u16x8*)&sL[poA]; }
    if (vB){ rBh = *(const u16x8*)&sH[poB]; rBl = *(const u16x8*)&sL[poB]; }
    *(u16x8*)&ldsHi[0][sA*8] = rAh; *(u16x8*)&ldsLo[0][sA*8] = rAl;
    if (hasB){ *(u16x8*)&ldsHi[0][sB*8] = rBh; *(u16x8*)&ldsLo[0][sB*8] = rBl; }

    int cur = 0;
    for (int icc=0; icc<8; ++icc){
        __syncthreads();
        if (icc+1 < 8){
            size_t co = (size_t)(icc+1)*8;
            rAh=(u16x8)0; rAl=(u16x8)0; rBh=(u16x8)0; rBl=(u16x8)0;
            if (vA){ rAh = *(const u16x8*)&sH[poA + co]; rAl = *(const u16x8*)&sL[poA + co]; }
            if (vB){ rBh = *(const u16x8*)&sH[poB + co]; rBl = *(const u16x8*)&sL[poB + co]; }
        }
        const unsigned short* bHp = ldsHi[cur];
        const unsigned short* bLp = ldsLo[cur];
        size_t i0 = ((size_t)((0*4 + par)*8 + icc))*512 + lane*8;
        size_t i1 = ((size_t)((1*4 + par)*8 + icc))*512 + lane*8;
        bf16x8 a0h = *(const bf16x8*)&wHi[i0];
        bf16x8 a0l = *(const bf16x8*)&wLo[i0];
        bf16x8 a1h = *(const bf16x8*)&wHi[i1];
        bf16x8 a1l = *(const bf16x8*)&wLo[i1];
        bf16x8 bh[4], bl[4];
        #pragma unroll
        for (int n=0;n<4;++n){
            int e = eb[n] + offs0;
            bh[n] = *(const bf16x8*)&bHp[e];
            bl[n] = *(const bf16x8*)&bLp[e];
        }
        #pragma unroll
        for (int n=0;n<4;++n){
            acc[0][n] = __builtin_amdgcn_mfma_f32_16x16x32_bf16(a0h, bh[n], acc[0][n], 0,0,0);
            acc[0][n] = __builtin_amdgcn_mfma_f32_16x16x32_bf16(a0h, bl[n], acc[0][n], 0,0,0);
            acc[0][n] = __builtin_amdgcn_mfma_f32_16x16x32_bf16(a0l, bh[n], acc[0][n], 0,0,0);
            acc[1][n] = __builtin_amdgcn_mfma_f32_16x16x32_bf16(a1h, bh[n], acc[1][n], 0,0,0);
            acc[1][n] = __builtin_amdgcn_mfma_f32_16x16x32_bf16(a1h, bl[n], acc[1][n], 0,0,0);
            acc[1][n] = __builtin_amdgcn_mfma_f32_16x16x32_bf16(a1l, bh[n], acc[1][n], 0,0,0);
        }
        if (icc+1 < 8){
            int nb = cur ^ 1;
            *(u16x8*)&ldsHi[nb][sA*8] = rAh; *(u16x8*)&ldsLo[nb][sA*8] = rAl;
            if (hasB){ *(u16x8*)&ldsHi[nb][sB*8] = rBh; *(u16x8*)&ldsLo[nb][sB*8] = rBl; }
        }
        cur ^= 1;
    }
    #pragma unroll
    for (int mm=0;mm<2;++mm){
        int ocb = mm*16 + (lane>>4)*4;
        #pragma unroll
        for (int n=0;n<4;++n){
            int oyr = r0 + wave*2 + (n>>1);
            int oxc = (n&1)*16 + (lane&15);
            int oy = 2*oyr + py, ox = 2*oxc + px;
            float* dst = y1 + ((size_t)tbl*32 + ocb)*4096 + oy*64 + ox;
            #pragma unroll
            for (int j=0;j<4;++j){
                float v = acc[mm][n][j] + Bb[ocb+j];
                dst[(size_t)j*4096] = LRELU(v);
            }
        }
    }
}

// ---------------------------------------------------------------------------
// deconv2: y1 (Ntb,32,64,64) -> out with (t,b) permute, k4 lhs_dil2 pad2, bias.
// ---------------------------------------------------------------------------
__global__ __launch_bounds__(256) void k_deconv2(const float* __restrict__ in,
    const float* __restrict__ W, const float* __restrict__ Bb, float* __restrict__ out,
    int tbOff)
{
    __shared__ float wl[512];
    int tid = threadIdx.x;
    for (int e=tid; e<512; e+=256) wl[e] = W[e];   // [ic][kh][kw], oc=1
    __syncthreads();
    int tbl = blockIdx.y;
    int tb = tbOff + tbl; int t = tb >> 5; int b = tb & 31;
    int idx4 = blockIdx.x*256 + tid;
    int oy = idx4 >> 5; int ox0 = (idx4 & 31)*4;
    int ph = oy & 1;
    const float* base = in + (size_t)tbl*131072;
    float acc0=0.f, acc1=0.f, acc2=0.f, acc3=0.f;
    int ix0 = ox0/2 - 1;
    for (int ic=0; ic<32; ++ic){
        const float* cp = base + ic*4096;
        #pragma unroll
        for (int kk=0; kk<2; ++kk){
            int kh = ph + 2*kk;
            int iy = (oy + kh - 2) >> 1;
            if (iy < 0 || iy > 63) continue;
            const float* rp = cp + (size_t)iy*64;
            float wv0 = (ix0 >= 0)   ? rp[ix0]   : 0.f;
            float wv1 = rp[ix0+1];
            float wv2 = rp[ix0+2];
            float wv3 = (ix0+3 <= 63) ? rp[ix0+3] : 0.f;
            float w0 = wl[ic*16 + kh*4 + 0];
            float w1 = wl[ic*16 + kh*4 + 1];
            float w2 = wl[ic*16 + kh*4 + 2];
            float w3 = wl[ic*16 + kh*4 + 3];
            acc0 += w0*wv0 + w2*wv1;        // p=0: kw 0,2
            acc2 += w0*wv1 + w2*wv2;        // p=2
            acc1 += w1*wv1 + w3*wv2;        // p=1: kw 1,3
            acc3 += w1*wv2 + w3*wv3;        // p=3
        }
    }
    float bv = Bb[0];
    float4 res = make_float4(acc0+bv, acc1+bv, acc2+bv, acc3+bv);
    float* op = out + ((size_t)(b*10 + t))*16384 + (size_t)oy*128 + ox0;
    *(float4*)op = res;
}

// ---------------------------------------------------------------------------
// Workspace (bytes), peak 121,700,352 — layout identical to rounds 5-9.
// ---------------------------------------------------------------------------
extern "C" void kernel_launch(void* const* d_in, const int* in_sizes, int n_in,
                              void* d_out, int out_size, void* d_ws, size_t ws_size,
                              hipStream_t stream)
{
    const float* x    = (const float*)d_in[0];
    const float* ew1  = (const float*)d_in[1];
    const float* eb1  = (const float*)d_in[2];
    const float* ew2  = (const float*)d_in[3];
    const float* eb2  = (const float*)d_in[4];
    const float* ewzr = (const float*)d_in[5];
    const float* ebzr = (const float*)d_in[6];
    const float* ewc  = (const float*)d_in[7];
    const float* ebc  = (const float*)d_in[8];
    const float* dwzr = (const float*)d_in[9];
    const float* dbzr = (const float*)d_in[10];
    const float* dwc  = (const float*)d_in[11];
    const float* dbc  = (const float*)d_in[12];
    const float* dw1  = (const float*)d_in[13];
    const float* db1  = (const float*)d_in[14];
    const float* dw2  = (const float*)d_in[15];
    const float* db2  = (const float*)d_in[16];
    float* out = (float*)d_out;
    char* ws = (char*)d_ws;

    unsigned short* e2hi = (unsigned short*)(ws + 0);
    unsigned short* e2lo = (unsigned short*)(ws + 41943040UL);
    float*          h32  = (float*)(ws + 83886080UL);
    unsigned short* hHi  = (unsigned short*)(ws + 92274688UL);
    unsigned short* hLo  = (unsigned short*)(ws + 96468992UL);
    unsigned short* rhHi = (unsigned short*)(ws + 100663296UL);
    unsigned short* rhLo = (unsigned short*)(ws + 104857600UL);
    float*          z32  = (float*)(ws + 109051904UL);
    unsigned short* A0   = (unsigned short*)(ws + 117440512UL);
    unsigned short* AzrH = A0;            unsigned short* AzrL = A0 + 458752;
    unsigned short* AcH  = A0 + 917504;   unsigned short* AcL  = A0 + 1146880;
    unsigned short* DzrH = A0 + 1376256;  unsigned short* DzrL = A0 + 1605632;
    unsigned short* DcH  = A0 + 1835008;  unsigned short* DcL  = A0 + 1949696;
    unsigned short* D1H  = A0 + 2064384;  unsigned short* D1L  = A0 + 2097152;
    float* e1c = (float*)(ws + 83886080UL);   // phase-1 overlay (40 MB)
    float* y1c = (float*)(ws + 83886080UL);   // phase-4 overlay (33.5 MB)

    // Phase 1: conv1 -> conv2 (e2 split channel-last), chunked x2
    for (int c=0; c<2; ++c){
        int off = c*160;
        k_conv1<<<dim3(16,160),256,0,stream>>>(x + (size_t)off*16384, ew1, eb1, e1c);
        k_conv2<<<dim3(4,160),256,0,stream>>>(e1c, ew2, eb2,
                                              e2hi + (size_t)off*65536,
                                              e2lo + (size_t)off*65536);
    }

    // Weight packing AFTER phase 1 (e1c overlay covers the pack region)
    k_prep<<<224,256,0,stream>>>(ewzr, 128, 0, 128, 57344, AzrH, AzrL);
    k_prep<<<112,256,0,stream>>>(ewc,  128, 0, 128, 28672, AcH,  AcL);
    k_prep<<<112,256,0,stream>>>(dwzr, 128, 64, 64, 28672, DzrH, DzrL);
    k_prep<<< 56,256,0,stream>>>(dwc,  128, 64, 64, 14336, DcH,  DcL);
    k_prep_d1<<<16,256,0,stream>>>(dw1, D1H, D1L);

    hipMemsetAsync(h32, 0, 8388608UL, stream);
    hipMemsetAsync(hHi, 0, 4194304UL, stream);
    hipMemsetAsync(hLo, 0, 4194304UL, stream);

    // Phase 2: encoder GRU scan (zr back at ROWS=8: 512 blocks, NT=4)
    for (int t=0; t<10; ++t){
        k_conv5f<0,8,4><<<512,256,0,stream>>>(
            e2hi + (size_t)t*65536, e2lo + (size_t)t*65536, 655360ULL, 8,
            hHi, hLo, 65536ULL, AzrH, AzrL, 16, ebzr,
            h32, nullptr, z32, rhHi, rhLo, nullptr, nullptr, nullptr);
        k_conv5f<1,4,2><<<512,256,0,stream>>>(
            e2hi + (size_t)t*65536, e2lo + (size_t)t*65536, 655360ULL, 8,
            rhHi, rhLo, 65536ULL, AcH, AcL, 16, ebc,
            h32, z32, nullptr, hHi, hLo, h32, nullptr, nullptr);
    }
    // Phase 3: decoder GRU scan; hs (bf16 hi/lo) overlays e2
    for (int t=0; t<10; ++t){
        k_conv5f<0,8,4><<<512,256,0,stream>>>(
            hHi, hLo, 65536ULL, 8,
            hHi, hLo, 65536ULL, DzrH, DzrL, 8, dbzr,
            h32, nullptr, z32, rhHi, rhLo, nullptr, nullptr, nullptr);
        k_conv5f<1,4,2><<<512,256,0,stream>>>(
            rhHi, rhLo, 65536ULL, 8,
            rhHi, rhLo, 65536ULL, DcH, DcL, 8, dbc,
            h32, z32, nullptr, hHi, hLo, h32,
            e2hi + (size_t)t*2097152, e2lo + (size_t)t*2097152);
    }
    // Phase 4: deconv1m (MFMA) -> deconv2, chunked x5 over tb (64 each)
    for (int c=0; c<5; ++c){
        int tbOff = c*64;
        k_deconv1m<<<1024,256,0,stream>>>(
            e2hi + (size_t)tbOff*65536, e2lo + (size_t)tbOff*65536,
            D1H, D1L, db1, y1c);
        k_deconv2<<<dim3(16,64),256,0,stream>>>(y1c, dw2, db2, out, tbOff);
    }
}

// Round 11
// 2797.316 us; speedup vs baseline: 1.0622x; 1.0543x over previous
//
#include <hip/hip_runtime.h>
#include <math.h>

#define LRELU(v) ((v) >= 0.f ? (v) : 0.2f*(v))

__device__ __forceinline__ float sigmoidf_(float x){ return 1.f/(1.f + expf(-x)); }

typedef __attribute__((ext_vector_type(8))) short bf16x8;
typedef __attribute__((ext_vector_type(4))) float f32x4;
typedef __attribute__((ext_vector_type(8))) unsigned short u16x8;
typedef __attribute__((ext_vector_type(4))) unsigned short u16x4;

__device__ __forceinline__ unsigned short bf16_rne(float x){
    union { float f; unsigned u; } v; v.f = x;
    unsigned r = v.u + 0x7fffu + ((v.u >> 16) & 1u);
    return (unsigned short)(r >> 16);
}
__device__ __forceinline__ float bf16_tof(unsigned short h){
    union { float f; unsigned u; } v; v.u = ((unsigned)h) << 16; return v.f;
}
__device__ __forceinline__ void bsplit(float x, unsigned short& hi, unsigned short& lo){
    hi = bf16_rne(x);
    lo = bf16_rne(x - bf16_tof(hi));
}

// ---------------------------------------------------------------------------
// conv1: x (Nimg,1,128,128) -> e1 CHANNEL-LAST bf16 hi/lo [img][4096][16],
// k3 s2 p1, bias+lrelu (split fused into epilogue).
// ---------------------------------------------------------------------------
__global__ __launch_bounds__(256) void k_conv1(const float* __restrict__ x,
    const float* __restrict__ W, const float* __restrict__ Bb,
    unsigned short* __restrict__ e1Hi, unsigned short* __restrict__ e1Lo)
{
    __shared__ float wl[144];
    __shared__ float bl[16];
    int tid = threadIdx.x;
    if (tid < 144) { int oc = tid/9, tap = tid%9; wl[tap*16+oc] = W[oc*9+tap]; }
    if (tid < 16) bl[tid] = Bb[tid];
    __syncthreads();
    int img = blockIdx.y;
    int px = blockIdx.x*256 + tid;
    int oy = px >> 6, ox = px & 63;
    const float* xin = x + (size_t)img*16384;
    float acc[16];
    #pragma unroll
    for (int o=0;o<16;++o) acc[o]=bl[o];
    #pragma unroll
    for (int kh=0; kh<3; ++kh){
        int iy = 2*oy + kh - 1;
        bool vy = (iy>=0 && iy<128);
        #pragma unroll
        for (int kw=0; kw<3; ++kw){
            int ix = 2*ox + kw - 1;
            float v = (vy && ix>=0 && ix<128) ? xin[iy*128+ix] : 0.f;
            int tap = kh*3+kw;
            #pragma unroll
            for (int o=0;o<16;++o) acc[o] += wl[tap*16+o]*v;
        }
    }
    size_t bo = ((size_t)img*4096 + px)*16;
    u16x8 h0, h1, l0, l1;
    #pragma unroll
    for (int o=0;o<8;++o){
        float v0 = LRELU(acc[o]);
        float v1 = LRELU(acc[o+8]);
        unsigned short hh, ll;
        bsplit(v0,hh,ll); h0[o]=hh; l0[o]=ll;
        bsplit(v1,hh,ll); h1[o]=hh; l1[o]=ll;
    }
    *(u16x8*)&e1Hi[bo]   = h0; *(u16x8*)&e1Hi[bo+8] = h1;
    *(u16x8*)&e1Lo[bo]   = l0; *(u16x8*)&e1Lo[bo+8] = l1;
}

// ---------------------------------------------------------------------------
// k_prep_c2: pack conv2 (3x3 s2, 16ic -> 64oc) weights into MFMA A-fragment
// order, taps padded 9->12 (3 ks of 4). grp = (mt2*2+icc)*3+ks, mt2 in [0,4).
// ---------------------------------------------------------------------------
__global__ __launch_bounds__(256) void k_prep_c2(const float* __restrict__ W,
    unsigned short* __restrict__ outHi, unsigned short* __restrict__ outLo)
{
    int id = blockIdx.x*256 + threadIdx.x;
    if (id >= 1536) return;
    int lane = id & 63;
    int grp = id >> 6;              // [0,24)
    int ks = grp % 3;
    int icc = (grp/3) & 1;
    int mt2 = grp / 6;              // [0,4)
    int oc = mt2*16 + (lane & 15);
    int t = ks*4 + (lane >> 4);
    u16x8 vh, vl;
    #pragma unroll
    for (int r=0;r<8;++r){
        int ic = icc*8 + r;
        float v = 0.f;
        if (t < 9) v = W[(((size_t)oc*16 + ic)*3 + t/3)*3 + (t%3)];
        unsigned short hh, ll; bsplit(v, hh, ll);
        vh[r]=hh; vl[r]=ll;
    }
    size_t base = ((size_t)grp)*512 + lane*8;
    *(u16x8*)&outHi[base] = vh;
    *(u16x8*)&outLo[base] = vl;
}

// ---------------------------------------------------------------------------
// k_conv2m: e1 ch-last bf16 hi/lo -> e2 split ch-last [img][1024][64],
// 3x3 s2 p1 via split-bf16 MFMA shift-GEMM. Block 256 (4 waves), tile
// 32oc x 8rows x 32cols. K = 12 padded taps x 16 ic -> 2 icc x 3 ks.
// LDS [17][66][8ic] hi/lo (35.9 KB), single-buffered. XCD decode (T1).
// grid 640 = 8 XCD x (2 ocBlk x 40 (img,rt) groups... decode below).
// ---------------------------------------------------------------------------
__global__ __launch_bounds__(256) void k_conv2m(
    const unsigned short* __restrict__ e1Hi, const unsigned short* __restrict__ e1Lo,
    const unsigned short* __restrict__ wHi, const unsigned short* __restrict__ wLo,
    const float* __restrict__ Bb,
    unsigned short* __restrict__ e2hi, unsigned short* __restrict__ e2lo)
{
    __shared__ __align__(16) unsigned short ldsHi[1122*8];
    __shared__ __align__(16) unsigned short ldsLo[1122*8];
    int tid = threadIdx.x;
    int lane = tid & 63, wave = tid >> 6;
    int bid = blockIdx.x;
    int m = bid & 7;
    int kk = bid >> 3;              // [0,80)
    int ocBlk = kk & 1;
    int g = kk >> 1;                // [0,40)
    int idx = m*40 + g;             // [0,320)
    int img = idx >> 2;             // [0,80)
    int rt  = idx & 3;
    int r0 = rt*8;

    const unsigned short* sH = e1Hi + (size_t)img*65536;
    const unsigned short* sL = e1Lo + (size_t)img*65536;

    int q = lane >> 4;
    int eb[4];
    #pragma unroll
    for (int n=0;n<4;++n){
        int ro = wave*2 + (n>>1);
        int oco = (n&1)*16 + (lane&15);
        eb[n] = (2*ro*66 + 2*oco)*8;
    }
    int offs[3];
    #pragma unroll
    for (int ks=0; ks<3; ++ks){
        int t = ks*4 + q;
        int dy = (t<9)? t/3 : 0;
        int dx = (t<9)? t%3 : 0;
        offs[ks] = (dy*66 + dx)*8;
    }

    f32x4 acc[2][4];
    #pragma unroll
    for (int mm=0;mm<2;++mm)
      #pragma unroll
      for (int n=0;n<4;++n) acc[mm][n] = (f32x4){0.f,0.f,0.f,0.f};

    for (int icc=0; icc<2; ++icc){
        __syncthreads();
        #pragma unroll
        for (int k=0;k<5;++k){
            int s = tid + k*256;
            if (s < 1122){
                int ly = s/66, lx = s - ly*66;
                int gy = 2*r0 - 1 + ly, gx = lx - 1;
                u16x8 vh=(u16x8)0, vl=(u16x8)0;
                if (gy>=0 && gy<64 && gx>=0 && gx<64){
                    size_t off = ((size_t)(gy*64+gx))*16 + icc*8;
                    vh = *(const u16x8*)&sH[off];
                    vl = *(const u16x8*)&sL[off];
                }
                *(u16x8*)&ldsHi[s*8] = vh;
                *(u16x8*)&ldsLo[s*8] = vl;
            }
        }
        __syncthreads();
        #pragma unroll
        for (int ks=0; ks<3; ++ks){
            size_t i0 = (((size_t)(ocBlk*2+0)*2 + icc)*3 + ks)*512 + lane*8;
            size_t i1 = (((size_t)(ocBlk*2+1)*2 + icc)*3 + ks)*512 + lane*8;
            bf16x8 a0h = *(const bf16x8*)&wHi[i0];
            bf16x8 a0l = *(const bf16x8*)&wLo[i0];
            bf16x8 a1h = *(const bf16x8*)&wHi[i1];
            bf16x8 a1l = *(const bf16x8*)&wLo[i1];
            bf16x8 bh[4], bl[4];
            #pragma unroll
            for (int n=0;n<4;++n){
                int e = eb[n] + offs[ks];
                bh[n] = *(const bf16x8*)&ldsHi[e];
                bl[n] = *(const bf16x8*)&ldsLo[e];
            }
            #pragma unroll
            for (int n=0;n<4;++n){
                acc[0][n] = __builtin_amdgcn_mfma_f32_16x16x32_bf16(a0h, bh[n], acc[0][n], 0,0,0);
                acc[0][n] = __builtin_amdgcn_mfma_f32_16x16x32_bf16(a0h, bl[n], acc[0][n], 0,0,0);
                acc[0][n] = __builtin_amdgcn_mfma_f32_16x16x32_bf16(a0l, bh[n], acc[0][n], 0,0,0);
                acc[1][n] = __builtin_amdgcn_mfma_f32_16x16x32_bf16(a1h, bh[n], acc[1][n], 0,0,0);
                acc[1][n] = __builtin_amdgcn_mfma_f32_16x16x32_bf16(a1h, bl[n], acc[1][n], 0,0,0);
                acc[1][n] = __builtin_amdgcn_mfma_f32_16x16x32_bf16(a1l, bh[n], acc[1][n], 0,0,0);
            }
        }
    }
    #pragma unroll
    for (int mm=0;mm<2;++mm){
        int oc = ocBlk*32 + mm*16 + (lane>>4)*4;
        f32x4 b4 = *(const f32x4*)&Bb[oc];
        #pragma unroll
        for (int n=0;n<4;++n){
            int px = (r0 + wave*2 + (n>>1))*32 + (n&1)*16 + (lane&15);
            size_t ii = ((size_t)img*1024 + px)*64 + oc;
            u16x4 hh4, hl4;
            #pragma unroll
            for (int j=0;j<4;++j){
                float v = acc[mm][n][j] + b4[j];
                v = LRELU(v);
                unsigned short hh,ll; bsplit(v,hh,ll);
                hh4[j]=hh; hl4[j]=ll;
            }
            *(u16x4*)&e2hi[ii] = hh4;
            *(u16x4*)&e2lo[ii] = hl4;
        }
    }
}

// ---------------------------------------------------------------------------
// k_prep: pack conv5 weights into MFMA A-fragment order, bf16 hi/lo.
// ---------------------------------------------------------------------------
__global__ __launch_bounds__(256) void k_prep(const float* __restrict__ W,
    int wIcTot, int wIcOff, int icTot, int total,
    unsigned short* __restrict__ outHi, unsigned short* __restrict__ outLo)
{
    int id = blockIdx.x*256 + threadIdx.x;
    if (id >= total) return;
    int lane = id & 63;
    int grp  = id >> 6;
    int ks = grp % 7;
    int rest = grp / 7;
    int iccTot = icTot >> 3;
    int oc = (rest / iccTot)*16 + (lane & 15);
    int t  = ks*4 + (lane >> 4);
    int icBase = (rest % iccTot)*8;
    u16x8 vh, vl;
    #pragma unroll
    for (int r=0;r<8;++r){
        float v = 0.f;
        if (t < 25) v = W[((size_t)oc*wIcTot + wIcOff + icBase + r)*25 + t];
        unsigned short hh, ll; bsplit(v, hh, ll);
        vh[r]=hh; vl[r]=ll;
    }
    size_t base = ((size_t)grp)*512 + lane*8;
    *(u16x8*)&outHi[base] = vh;
    *(u16x8*)&outLo[base] = vl;
}

// ---------------------------------------------------------------------------
// k_prep_d1: pack deconv1 (4x4, lhs_dil 2) weights per parity class.
// ---------------------------------------------------------------------------
__global__ __launch_bounds__(256) void k_prep_d1(const float* __restrict__ W,
    unsigned short* __restrict__ outHi, unsigned short* __restrict__ outLo)
{
    int id = blockIdx.x*256 + threadIdx.x;
    if (id >= 4096) return;
    int lane = id & 63;
    int grp = id >> 6;
    int icc = grp & 7; int par = (grp>>3)&3; int mt = grp>>5;
    int py = par>>1, px = par&1;
    int oc = mt*16 + (lane&15);
    int t = lane>>4; int a = t>>1, bb = t&1;
    int kh = 2*a+py, kw = 2*bb+px;
    u16x8 vh, vl;
    #pragma unroll
    for (int r=0;r<8;++r){
        int ic = icc*8 + r;
        float v = W[(((size_t)oc*64 + ic)*4 + kh)*4 + kw];
        unsigned short hh, ll; bsplit(v, hh, ll);
        vh[r]=hh; vl[r]=ll;
    }
    size_t base = ((size_t)grp)*512 + lane*8;
    *(u16x8*)&outHi[base] = vh;
    *(u16x8*)&outLo[base] = vl;
}

// ---------------------------------------------------------------------------
// k_conv5f: 5x5 pad2 s1 over 32x32, split-bf16 MFMA shift-GEMM, fused GRU
// pointwise epilogue. Double-buffered LDS input (T14) + bulk per-icc weight
// hoist + s_setprio(1) around the MFMA section (T5).
// ---------------------------------------------------------------------------
template<int MODE, int ROWS, int NOC>
__global__ __launch_bounds__(256) void k_conv5f(
    const unsigned short* __restrict__ aHi, const unsigned short* __restrict__ aLo,
    unsigned long long strA, int iccA,
    const unsigned short* __restrict__ inbHi, const unsigned short* __restrict__ inbLo,
    unsigned long long strB,
    const unsigned short* __restrict__ wHi, const unsigned short* __restrict__ wLo,
    int iccTot,
    const float* __restrict__ bias,
    const float* __restrict__ h32,
    const float* __restrict__ z32in,
    float* __restrict__ z32out,
    unsigned short* __restrict__ oHi, unsigned short* __restrict__ oLo,
    float* __restrict__ h32out,
    unsigned short* __restrict__ hsHi, unsigned short* __restrict__ hsLo)
{
    constexpr int RW = ROWS/4;          // rows per wave
    constexpr int NT = ROWS/2;          // n-tiles per wave
    constexpr int SPOS = (ROWS+4)*36;
    constexpr int SPAN = (32/ROWS)*4;   // per-XCD (batch,rowtile) span
    __shared__ __align__(16) unsigned short ldsHi[2][SPOS*8];
    __shared__ __align__(16) unsigned short ldsLo[2][SPOS*8];
    int tid = threadIdx.x;
    int lane = tid & 63, wave = tid >> 6;
    int bid = blockIdx.x;
    int m = bid & 7;
    int kk = bid >> 3;
    int ocBlk = kk % NOC;
    int g = kk / NOC;
    int idx = m*SPAN + g;
    int batch = idx & 31;
    int r0 = (idx >> 5)*ROWS;

    // staging geometry (icc-invariant)
    int sA = tid;
    int lyA = sA/36, lxA = sA - lyA*36;
    int gyA = r0 - 2 + lyA, gxA = lxA - 2;
    bool vA = (gyA>=0 && gyA<32 && gxA>=0 && gxA<32);
    size_t poA = ((size_t)(gyA*32+gxA))*64;
    int sB = tid + 256;
    bool hasB = (sB < SPOS);
    int lyB = sB/36, lxB = sB - lyB*36;
    int gyB = r0 - 2 + lyB, gxB = lxB - 2;
    bool vB = hasB && (gyB>=0 && gyB<32 && gxB>=0 && gxB<32);
    size_t poB = ((size_t)(gyB*32+gxB))*64;

    int offs[7];
    #pragma unroll
    for (int ks=0; ks<7; ++ks){
        int t = ks*4 + (lane>>4);
        int dy = (t<25)? t/5 : 2;
        int dx = (t<25)? t%5 : 2;
        offs[ks] = (dy*36 + dx)*8;
    }
    int eb[NT];
    #pragma unroll
    for (int n=0;n<NT;++n)
        eb[n] = (((wave*RW + (n>>1))*36) + (n&1)*16 + (lane&15))*8;

    f32x4 acc[2][NT];
    #pragma unroll
    for (int mm=0;mm<2;++mm)
      #pragma unroll
      for (int n=0;n<NT;++n) acc[mm][n] = (f32x4){0.f,0.f,0.f,0.f};

    u16x8 rAh=(u16x8)0, rAl=(u16x8)0, rBh=(u16x8)0, rBl=(u16x8)0;

    // ---- LOAD icc=0 into regs
    {
        const unsigned short* sHp; const unsigned short* sLp; int icLoc;
        if (0 < iccA){ sHp = aHi + (size_t)batch*strA; sLp = aLo + (size_t)batch*strA; icLoc = 0; }
        else         { sHp = inbHi + (size_t)batch*strB; sLp = inbLo + (size_t)batch*strB; icLoc = -iccA; }
        if (vA){ rAh = *(const u16x8*)&sHp[poA + icLoc*8]; rAl = *(const u16x8*)&sLp[poA + icLoc*8]; }
        if (vB){ rBh = *(const u16x8*)&sHp[poB + icLoc*8]; rBl = *(const u16x8*)&sLp[poB + icLoc*8]; }
    }
    *(u16x8*)&ldsHi[0][sA*8] = rAh; *(u16x8*)&ldsLo[0][sA*8] = rAl;
    if (hasB){ *(u16x8*)&ldsHi[0][sB*8] = rBh; *(u16x8*)&ldsLo[0][sB*8] = rBl; }

    int cur = 0;
    for (int icc = 0; icc < iccTot; ++icc){
        __syncthreads();
        // ---- issue next-icc input loads (no wait)
        if (icc+1 < iccTot){
            int icn = icc+1;
            const unsigned short* sHp; const unsigned short* sLp; int icLoc;
            if (icn < iccA){ sHp = aHi + (size_t)batch*strA; sLp = aLo + (size_t)batch*strA; icLoc = icn; }
            else           { sHp = inbHi + (size_t)batch*strB; sLp = inbLo + (size_t)batch*strB; icLoc = icn - iccA; }
            rAh=(u16x8)0; rAl=(u16x8)0; rBh=(u16x8)0; rBl=(u16x8)0;
            if (vA){ rAh = *(const u16x8*)&sHp[poA + icLoc*8]; rAl = *(const u16x8*)&sLp[poA + icLoc*8]; }
            if (vB){ rBh = *(const u16x8*)&sHp[poB + icLoc*8]; rBl = *(const u16x8*)&sLp[poB + icLoc*8]; }
        }
        // ---- bulk weight hoist
        bf16x8 wv[28];
        #pragma unroll
        for (int ks=0; ks<7; ++ks){
            size_t i0 = (((size_t)(ocBlk*2+0)*iccTot + icc)*7 + ks)*512 + lane*8;
            size_t i1 = (((size_t)(ocBlk*2+1)*iccTot + icc)*7 + ks)*512 + lane*8;
            wv[ks*4+0] = *(const bf16x8*)&wHi[i0];
            wv[ks*4+1] = *(const bf16x8*)&wLo[i0];
            wv[ks*4+2] = *(const bf16x8*)&wHi[i1];
            wv[ks*4+3] = *(const bf16x8*)&wLo[i1];
        }
        // ---- compute on buf[cur]
        const unsigned short* bHp = ldsHi[cur];
        const unsigned short* bLp = ldsLo[cur];
        __builtin_amdgcn_s_setprio(1);
        #pragma unroll
        for (int ks=0; ks<7; ++ks){
            bf16x8 a0h = wv[ks*4+0];
            bf16x8 a0l = wv[ks*4+1];
            bf16x8 a1h = wv[ks*4+2];
            bf16x8 a1l = wv[ks*4+3];
            bf16x8 bh[NT], bl[NT];
            #pragma unroll
            for (int n=0;n<NT;++n){
                int e = eb[n] + offs[ks];
                bh[n] = *(const bf16x8*)&bHp[e];
                bl[n] = *(const bf16x8*)&bLp[e];
            }
            #pragma unroll
            for (int n=0;n<NT;++n){
                acc[0][n] = __builtin_amdgcn_mfma_f32_16x16x32_bf16(a0h, bh[n], acc[0][n], 0,0,0);
                acc[0][n] = __builtin_amdgcn_mfma_f32_16x16x32_bf16(a0h, bl[n], acc[0][n], 0,0,0);
                acc[0][n] = __builtin_amdgcn_mfma_f32_16x16x32_bf16(a0l, bh[n], acc[0][n], 0,0,0);
                acc[1][n] = __builtin_amdgcn_mfma_f32_16x16x32_bf16(a1h, bh[n], acc[1][n], 0,0,0);
                acc[1][n] = __builtin_amdgcn_mfma_f32_16x16x32_bf16(a1h, bl[n], acc[1][n], 0,0,0);
                acc[1][n] = __builtin_amdgcn_mfma_f32_16x16x32_bf16(a1l, bh[n], acc[1][n], 0,0,0);
            }
        }
        __builtin_amdgcn_s_setprio(0);
        // ---- write prefetched input regs to the other buffer
        if (icc+1 < iccTot){
            int nb = cur ^ 1;
            *(u16x8*)&ldsHi[nb][sA*8] = rAh; *(u16x8*)&ldsLo[nb][sA*8] = rAl;
            if (hasB){ *(u16x8*)&ldsHi[nb][sB*8] = rBh; *(u16x8*)&ldsLo[nb][sB*8] = rBl; }
        }
        cur ^= 1;
    }

    if (MODE == 0){
        bool rside = (ocBlk < 2);
        #pragma unroll
        for (int mm=0;mm<2;++mm){
            int ocBase = ocBlk*32 + mm*16 + (lane>>4)*4;
            f32x4 b4 = *(const f32x4*)&bias[ocBase];
            #pragma unroll
            for (int n=0;n<NT;++n){
                int px = (r0 + wave*RW + (n>>1))*32 + (n&1)*16 + (lane&15);
                if (rside){
                    size_t ii = ((size_t)batch*1024 + px)*64 + ocBase;
                    f32x4 h4 = *(const f32x4*)&h32[ii];
                    u16x4 rH, rL;
                    #pragma unroll
                    for (int j=0;j<4;++j){
                        float r = sigmoidf_(acc[mm][n][j] + b4[j]);
                        unsigned short hh,ll; bsplit(r*h4[j],hh,ll);
                        rH[j]=hh; rL[j]=ll;
                    }
                    *(u16x4*)&oHi[ii] = rH;
                    *(u16x4*)&oLo[ii] = rL;
                } else {
                    size_t ii = ((size_t)batch*1024 + px)*64 + ocBase - 64;
                    f32x4 z;
                    #pragma unroll
                    for (int j=0;j<4;++j) z[j] = sigmoidf_(acc[mm][n][j] + b4[j]);
                    *(f32x4*)&z32out[ii] = z;
                }
            }
        }
    } else {
        #pragma unroll
        for (int mm=0;mm<2;++mm){
            int oc = ocBlk*32 + mm*16 + (lane>>4)*4;
            f32x4 b4 = *(const f32x4*)&bias[oc];
            #pragma unroll
            for (int n=0;n<NT;++n){
                int px = (r0 + wave*RW + (n>>1))*32 + (n&1)*16 + (lane&15);
                size_t ii = ((size_t)batch*1024 + px)*64 + oc;
                f32x4 h4 = *(const f32x4*)&h32[ii];
                f32x4 z4 = *(const f32x4*)&z32in[ii];
                f32x4 hn; u16x4 hh4, hl4;
                #pragma unroll
                for (int j=0;j<4;++j){
                    float c = tanhf(acc[mm][n][j] + b4[j]);
                    hn[j] = (1.f - z4[j])*h4[j] + z4[j]*c;
                    unsigned short hh,ll; bsplit(hn[j],hh,ll);
                    hh4[j]=hh; hl4[j]=ll;
                }
                *(f32x4*)&h32out[ii] = hn;
                *(u16x4*)&oHi[ii] = hh4;
                *(u16x4*)&oLo[ii] = hl4;
                if (hsHi){
                    *(u16x4*)&hsHi[ii] = hh4;
                    *(u16x4*)&hsLo[ii] = hl4;
                }
            }
        }
    }
}

// ---------------------------------------------------------------------------
// k_deconv1m: hs (tb,1024px,64ic bf16 hi/lo) -> y1 (tb,32,64,64) fp32,
// k4 lhs_dil2 pad2 as 4 parity-class 2x2 convs via split-bf16 MFMA.
// ---------------------------------------------------------------------------
__global__ __launch_bounds__(256) void k_deconv1m(
    const unsigned short* __restrict__ hsHi, const unsigned short* __restrict__ hsLo,
    const unsigned short* __restrict__ wHi, const unsigned short* __restrict__ wLo,
    const float* __restrict__ Bb, float* __restrict__ y1)
{
    __shared__ __align__(16) unsigned short ldsHi[2][340*8];
    __shared__ __align__(16) unsigned short ldsLo[2][340*8];
    int tid = threadIdx.x;
    int lane = tid & 63, wave = tid >> 6;
    int bid = blockIdx.x;
    int m = bid & 7;
    int kk = bid >> 3;
    int par = kk & 3;
    int g = kk >> 2;
    int idx = m*32 + g;
    int tbl = idx & 63;
    int r0 = (idx >> 6)*8;
    int py = par >> 1, px = par & 1;
    const unsigned short* sH = hsHi + (size_t)tbl*65536;
    const unsigned short* sL = hsLo + (size_t)tbl*65536;

    int sA = tid;
    int lyA = sA/34, lxA = sA - lyA*34;
    int gyA = r0 - 1 + lyA, gxA = lxA - 1;
    bool vA = (gyA>=0 && gyA<32 && gxA>=0 && gxA<32);
    size_t poA = ((size_t)(gyA*32+gxA))*64;
    int sB = tid + 256;
    bool hasB = (sB < 340);
    int lyB = sB/34, lxB = sB - lyB*34;
    int gyB = r0 - 1 + lyB, gxB = lxB - 1;
    bool vB = hasB && (gyB>=0 && gyB<32 && gxB>=0 && gxB<32);
    size_t poB = ((size_t)(gyB*32+gxB))*64;

    int offs0 = ((lane>>5)*34 + ((lane>>4)&1))*8;
    int eb[4];
    #pragma unroll
    for (int n=0;n<4;++n)
        eb[n] = (((wave*2 + (n>>1)) + py)*34 + (n&1)*16 + (lane&15) + px)*8;

    f32x4 acc[2][4];
    #pragma unroll
    for (int mm=0;mm<2;++mm)
      #pragma unroll
      for (int n=0;n<4;++n) acc[mm][n] = (f32x4){0.f,0.f,0.f,0.f};

    u16x8 rAh=(u16x8)0, rAl=(u16x8)0, rBh=(u16x8)0, rBl=(u16x8)0;
    if (vA){ rAh = *(const u16x8*)&sH[poA]; rAl = *(const u16x8*)&sL[poA]; }
    if (vB){ rBh = *(const u16x8*)&sH[poB]; rBl = *(const u16x8*)&sL[poB]; }
    *(u16x8*)&ldsHi[0][sA*8] = rAh; *(u16x8*)&ldsLo[0][sA*8] = rAl;
    if (hasB){ *(u16x8*)&ldsHi[0][sB*8] = rBh; *(u16x8*)&ldsLo[0][sB*8] = rBl; }

    int cur = 0;
    for (int icc=0; icc<8; ++icc){
        __syncthreads();
        if (icc+1 < 8){
            size_t co = (size_t)(icc+1)*8;
            rAh=(u16x8)0; rAl=(u16x8)0; rBh=(u16x8)0; rBl=(u16x8)0;
            if (vA){ rAh = *(const u16x8*)&sH[poA + co]; rAl = *(const u16x8*)&sL[poA + co]; }
            if (vB){ rBh = *(const u16x8*)&sH[poB + co]; rBl = *(const u16x8*)&sL[poB + co]; }
        }
        const unsigned short* bHp = ldsHi[cur];
        const unsigned short* bLp = ldsLo[cur];
        size_t i0 = ((size_t)((0*4 + par)*8 + icc))*512 + lane*8;
        size_t i1 = ((size_t)((1*4 + par)*8 + icc))*512 + lane*8;
        bf16x8 a0h = *(const bf16x8*)&wHi[i0];
        bf16x8 a0l = *(const bf16x8*)&wLo[i0];
        bf16x8 a1h = *(const bf16x8*)&wHi[i1];
        bf16x8 a1l = *(const bf16x8*)&wLo[i1];
        bf16x8 bh[4], bl[4];
        #pragma unroll
        for (int n=0;n<4;++n){
            int e = eb[n] + offs0;
            bh[n] = *(const bf16x8*)&bHp[e];
            bl[n] = *(const bf16x8*)&bLp[e];
        }
        #pragma unroll
        for (int n=0;n<4;++n){
            acc[0][n] = __builtin_amdgcn_mfma_f32_16x16x32_bf16(a0h, bh[n], acc[0][n], 0,0,0);
            acc[0][n] = __builtin_amdgcn_mfma_f32_16x16x32_bf16(a0h, bl[n], acc[0][n], 0,0,0);
            acc[0][n] = __builtin_amdgcn_mfma_f32_16x16x32_bf16(a0l, bh[n], acc[0][n], 0,0,0);
            acc[1][n] = __builtin_amdgcn_mfma_f32_16x16x32_bf16(a1h, bh[n], acc[1][n], 0,0,0);
            acc[1][n] = __builtin_amdgcn_mfma_f32_16x16x32_bf16(a1h, bl[n], acc[1][n], 0,0,0);
            acc[1][n] = __builtin_amdgcn_mfma_f32_16x16x32_bf16(a1l, bh[n], acc[1][n], 0,0,0);
        }
        if (icc+1 < 8){
            int nb = cur ^ 1;
            *(u16x8*)&ldsHi[nb][sA*8] = rAh; *(u16x8*)&ldsLo[nb][sA*8] = rAl;
            if (hasB){ *(u16x8*)&ldsHi[nb][sB*8] = rBh; *(u16x8*)&ldsLo[nb][sB*8] = rBl; }
        }
        cur ^= 1;
    }
    #pragma unroll
    for (int mm=0;mm<2;++mm){
        int ocb = mm*16 + (lane>>4)*4;
        #pragma unroll
        for (int n=0;n<4;++n){
            int oyr = r0 + wave*2 + (n>>1);
            int oxc = (n&1)*16 + (lane&15);
            int oy = 2*oyr + py, ox = 2*oxc + px;
            float* dst = y1 + ((size_t)tbl*32 + ocb)*4096 + oy*64 + ox;
            #pragma unroll
            for (int j=0;j<4;++j){
                float v = acc[mm][n][j] + Bb[ocb+j];
                dst[(size_t)j*4096] = LRELU(v);
            }
        }
    }
}

// ---------------------------------------------------------------------------
// deconv2: y1 (Ntb,32,64,64) -> out with (t,b) permute, k4 lhs_dil2 pad2, bias.
// ---------------------------------------------------------------------------
__global__ __launch_bounds__(256) void k_deconv2(const float* __restrict__ in,
    const float* __restrict__ W, const float* __restrict__ Bb, float* __restrict__ out,
    int tbOff)
{
    __shared__ float wl[512];
    int tid = threadIdx.x;
    for (int e=tid; e<512; e+=256) wl[e] = W[e];   // [ic][kh][kw], oc=1
    __syncthreads();
    int tbl = blockIdx.y;
    int tb = tbOff + tbl; int t = tb >> 5; int b = tb & 31;
    int idx4 = blockIdx.x*256 + tid;
    int oy = idx4 >> 5; int ox0 = (idx4 & 31)*4;
    int ph = oy & 1;
    const float* base = in + (size_t)tbl*131072;
    float acc0=0.f, acc1=0.f, acc2=0.f, acc3=0.f;
    int ix0 = ox0/2 - 1;
    for (int ic=0; ic<32; ++ic){
        const float* cp = base + ic*4096;
        #pragma unroll
        for (int kk=0; kk<2; ++kk){
            int kh = ph + 2*kk;
            int iy = (oy + kh - 2) >> 1;
            if (iy < 0 || iy > 63) continue;
            const float* rp = cp + (size_t)iy*64;
            float wv0 = (ix0 >= 0)   ? rp[ix0]   : 0.f;
            float wv1 = rp[ix0+1];
            float wv2 = rp[ix0+2];
            float wv3 = (ix0+3 <= 63) ? rp[ix0+3] : 0.f;
            float w0 = wl[ic*16 + kh*4 + 0];
            float w1 = wl[ic*16 + kh*4 + 1];
            float w2 = wl[ic*16 + kh*4 + 2];
            float w3 = wl[ic*16 + kh*4 + 3];
            acc0 += w0*wv0 + w2*wv1;        // p=0: kw 0,2
            acc2 += w0*wv1 + w2*wv2;        // p=2
            acc1 += w1*wv1 + w3*wv2;        // p=1: kw 1,3
            acc3 += w1*wv2 + w3*wv3;        // p=3
        }
    }
    float bv = Bb[0];
    float4 res = make_float4(acc0+bv, acc1+bv, acc2+bv, acc3+bv);
    float* op = out + ((size_t)(b*10 + t))*16384 + (size_t)oy*128 + ox0;
    *(float4*)op = res;
}

// ---------------------------------------------------------------------------
// Workspace (bytes), peak 121,749,504:
//  [0        , 41943040): e2hi  / hsHi overlay (decoder)
//  [41943040 , 83886080): e2lo  / hsLo overlay
//  [83886080 , 92274688): h32   [92274688,96468992): hHi  [96468992,100663296): hLo
//  [100663296,104857600): rhHi  [104857600,109051904): rhLo
//  [109051904,117440512): z32
//  [117440512,121749504): weight packs (Azr,Ac,Dzr,Dc,D1,C2 x hi/lo)
//  Phase 1: e1c hi/lo (21 MB) overlays [83886080,104857600) — outside packs.
//  Phase 4: y1c (33.5 MB) overlays [83886080,117440512).
// ---------------------------------------------------------------------------
extern "C" void kernel_launch(void* const* d_in, const int* in_sizes, int n_in,
                              void* d_out, int out_size, void* d_ws, size_t ws_size,
                              hipStream_t stream)
{
    const float* x    = (const float*)d_in[0];
    const float* ew1  = (const float*)d_in[1];
    const float* eb1  = (const float*)d_in[2];
    const float* ew2  = (const float*)d_in[3];
    const float* eb2  = (const float*)d_in[4];
    const float* ewzr = (const float*)d_in[5];
    const float* ebzr = (const float*)d_in[6];
    const float* ewc  = (const float*)d_in[7];
    const float* ebc  = (const float*)d_in[8];
    const float* dwzr = (const float*)d_in[9];
    const float* dbzr = (const float*)d_in[10];
    const float* dwc  = (const float*)d_in[11];
    const float* dbc  = (const float*)d_in[12];
    const float* dw1  = (const float*)d_in[13];
    const float* db1  = (const float*)d_in[14];
    const float* dw2  = (const float*)d_in[15];
    const float* db2  = (const float*)d_in[16];
    float* out = (float*)d_out;
    char* ws = (char*)d_ws;

    unsigned short* e2hi = (unsigned short*)(ws + 0);
    unsigned short* e2lo = (unsigned short*)(ws + 41943040UL);
    float*          h32  = (float*)(ws + 83886080UL);
    unsigned short* hHi  = (unsigned short*)(ws + 92274688UL);
    unsigned short* hLo  = (unsigned short*)(ws + 96468992UL);
    unsigned short* rhHi = (unsigned short*)(ws + 100663296UL);
    unsigned short* rhLo = (unsigned short*)(ws + 104857600UL);
    float*          z32  = (float*)(ws + 109051904UL);
    unsigned short* A0   = (unsigned short*)(ws + 117440512UL);
    unsigned short* AzrH = A0;            unsigned short* AzrL = A0 + 458752;
    unsigned short* AcH  = A0 + 917504;   unsigned short* AcL  = A0 + 1146880;
    unsigned short* DzrH = A0 + 1376256;  unsigned short* DzrL = A0 + 1605632;
    unsigned short* DcH  = A0 + 1835008;  unsigned short* DcL  = A0 + 1949696;
    unsigned short* D1H  = A0 + 2064384;  unsigned short* D1L  = A0 + 2097152;
    unsigned short* C2H  = A0 + 2129920;  unsigned short* C2L  = A0 + 2142208;
    unsigned short* e1cH = (unsigned short*)(ws + 83886080UL);   // 10.5 MB
    unsigned short* e1cL = (unsigned short*)(ws + 94371840UL);   // 10.5 MB
    float* y1c = (float*)(ws + 83886080UL);   // phase-4 overlay (33.5 MB)

    // conv2 weight pack (needed by phase 1)
    k_prep_c2<<<6,256,0,stream>>>(ew2, C2H, C2L);

    // Phase 1: conv1 -> conv2m (both MFMA-era, e1 ch-last bf16), chunked x4
    for (int c=0; c<4; ++c){
        int off = c*80;
        k_conv1<<<dim3(16,80),256,0,stream>>>(x + (size_t)off*16384, ew1, eb1,
                                              e1cH, e1cL);
        k_conv2m<<<640,256,0,stream>>>(e1cH, e1cL, C2H, C2L, eb2,
                                       e2hi + (size_t)off*65536,
                                       e2lo + (size_t)off*65536);
    }

    // Remaining weight packs (pack region is outside the e1c overlay now,
    // but keep the proven order: after phase 1)
    k_prep<<<224,256,0,stream>>>(ewzr, 128, 0, 128, 57344, AzrH, AzrL);
    k_prep<<<112,256,0,stream>>>(ewc,  128, 0, 128, 28672, AcH,  AcL);
    k_prep<<<112,256,0,stream>>>(dwzr, 128, 64, 64, 28672, DzrH, DzrL);
    k_prep<<< 56,256,0,stream>>>(dwc,  128, 64, 64, 14336, DcH,  DcL);
    k_prep_d1<<<16,256,0,stream>>>(dw1, D1H, D1L);

    hipMemsetAsync(h32, 0, 8388608UL, stream);
    hipMemsetAsync(hHi, 0, 4194304UL, stream);
    hipMemsetAsync(hLo, 0, 4194304UL, stream);

    // Phase 2: encoder GRU scan
    for (int t=0; t<10; ++t){
        k_conv5f<0,8,4><<<512,256,0,stream>>>(
            e2hi + (size_t)t*65536, e2lo + (size_t)t*65536, 655360ULL, 8,
            hHi, hLo, 65536ULL, AzrH, AzrL, 16, ebzr,
            h32, nullptr, z32, rhHi, rhLo, nullptr, nullptr, nullptr);
        k_conv5f<1,4,2><<<512,256,0,stream>>>(
            e2hi + (size_t)t*65536, e2lo + (size_t)t*65536, 655360ULL, 8,
            rhHi, rhLo, 65536ULL, AcH, AcL, 16, ebc,
            h32, z32, nullptr, hHi, hLo, h32, nullptr, nullptr);
    }
    // Phase 3: decoder GRU scan; hs (bf16 hi/lo) overlays e2
    for (int t=0; t<10; ++t){
        k_conv5f<0,8,4><<<512,256,0,stream>>>(
            hHi, hLo, 65536ULL, 8,
            hHi, hLo, 65536ULL, DzrH, DzrL, 8, dbzr,
            h32, nullptr, z32, rhHi, rhLo, nullptr, nullptr, nullptr);
        k_conv5f<1,4,2><<<512,256,0,stream>>>(
            rhHi, rhLo, 65536ULL, 8,
            rhHi, rhLo, 65536ULL, DcH, DcL, 8, dbc,
            h32, z32, nullptr, hHi, hLo, h32,
            e2hi + (size_t)t*2097152, e2lo + (size_t)t*2097152);
    }
    // Phase 4: deconv1m (MFMA) -> deconv2, chunked x5 over tb (64 each)
    for (int c=0; c<5; ++c){
        int tbOff = c*64;
        k_deconv1m<<<1024,256,0,stream>>>(
            e2hi + (size_t)tbOff*65536, e2lo + (size_t)tbOff*65536,
            D1H, D1L, db1, y1c);
        k_deconv2<<<dim3(16,64),256,0,stream>>>(y1c, dw2, db2, out, tbOff);
    }
}